// Round 1
// baseline (1377.506 us; speedup 1.0000x reference)
//
#include <hip/hip_runtime.h>

#define N_NODES 100000
#define N_EDGES 600000
#define N_GRAPHS 5000
#define IN_DIM 11
#define HID 128
#define NREST 4
#define BN_EPS 1e-5f
#define SCAN_BS 256
#define NBLK ((N_NODES + SCAN_BS - 1) / SCAN_BS)   // 391

// ---------------- utility: zero the small control buffers ----------------
__global__ void k_zero(int* deg, int* gstart, int* gend, float* stats) {
    int i = blockIdx.x * 256 + threadIdx.x;
    if (i < N_NODES) deg[i] = 0;
    if (i < N_GRAPHS) { gstart[i] = 0; gend[i] = 0; }
    if (i < 5 * 2 * HID) stats[i] = 0.f;
}

// ---------------- CSR build (by dst) ----------------
__global__ void k_deg(const int* __restrict__ ei, int* __restrict__ deg) {
    int e = blockIdx.x * 256 + threadIdx.x;
    if (e < N_EDGES) atomicAdd(&deg[ei[N_EDGES + e]], 1);
}

__global__ void k_scan_a(const int* __restrict__ deg, int* __restrict__ rowstart,
                         int* __restrict__ bsum) {
    __shared__ int sh[SCAN_BS];
    int t = threadIdx.x, i = blockIdx.x * SCAN_BS + t;
    int v = (i < N_NODES) ? deg[i] : 0;
    sh[t] = v;
    __syncthreads();
    for (int off = 1; off < SCAN_BS; off <<= 1) {
        int add = (t >= off) ? sh[t - off] : 0;
        __syncthreads();
        sh[t] += add;
        __syncthreads();
    }
    if (i < N_NODES) rowstart[i] = sh[t] - v;           // exclusive (block-local)
    if (t == SCAN_BS - 1) bsum[blockIdx.x] = sh[t];
}

__global__ void k_scan_b(const int* __restrict__ bsum, int* __restrict__ boff) {
    __shared__ int sh[512];
    int t = threadIdx.x;
    int v = (t < NBLK) ? bsum[t] : 0;
    sh[t] = v;
    __syncthreads();
    for (int off = 1; off < 512; off <<= 1) {
        int add = (t >= off) ? sh[t - off] : 0;
        __syncthreads();
        sh[t] += add;
        __syncthreads();
    }
    if (t < NBLK) boff[t] = sh[t] - v;                  // exclusive
}

__global__ void k_scan_c(int* __restrict__ rowstart, const int* __restrict__ boff,
                         int* __restrict__ cur) {
    int i = blockIdx.x * 256 + threadIdx.x;
    if (i < N_NODES) {
        int v = rowstart[i] + boff[i / SCAN_BS];
        rowstart[i] = v;
        cur[i] = v;
    }
    if (i == 0) rowstart[N_NODES] = N_EDGES;
}

__global__ void k_fill(const int* __restrict__ ei, const float* __restrict__ ea,
                       int* __restrict__ cur, int* __restrict__ csr_src,
                       float* __restrict__ csr_ea) {
    int e = blockIdx.x * 256 + threadIdx.x;
    if (e < N_EDGES) {
        int d = ei[N_EDGES + e];
        int p = atomicAdd(&cur[d], 1);
        csr_src[p] = ei[e];
        csr_ea[3 * p + 0] = ea[3 * e + 0];
        csr_ea[3 * p + 1] = ea[3 * e + 1];
        csr_ea[3 * p + 2] = ea[3 * e + 2];
    }
}

// ---------------- layer-0 aggregation (11 channels), writes Z0 = (1+eps)*x + aggr ----------
__global__ void k_agg0(const float* __restrict__ x, const int* __restrict__ rowstart,
                       const int* __restrict__ csr_src, const float* __restrict__ csr_ea,
                       const float* __restrict__ ew, const float* __restrict__ eb,
                       const float* __restrict__ epsp, float* __restrict__ Z0) {
    int wave = (blockIdx.x * blockDim.x + threadIdx.x) >> 6;
    int lane = threadIdx.x & 63;
    if (wave >= N_NODES) return;
    int n = wave;
    if (lane >= IN_DIM) return;
    int c = lane;
    float w0 = ew[0 * IN_DIM + c], w1 = ew[1 * IN_DIM + c], w2 = ew[2 * IN_DIM + c];
    float bb = eb[c];
    float acc = 0.f;
    int i1 = rowstart[n + 1];
    for (int i = rowstart[n]; i < i1; ++i) {
        int s = csr_src[i];
        float ea0 = csr_ea[3 * i], ea1 = csr_ea[3 * i + 1], ea2 = csr_ea[3 * i + 2];
        float m = x[s * IN_DIM + c] + ea0 * w0 + ea1 * w1 + ea2 * w2 + bb;
        acc += fmaxf(m, 0.f);
    }
    float epsv = 1.0f + epsp[0];
    Z0[n * IN_DIM + c] = epsv * x[n * IN_DIM + c] + acc;
}

// ---------------- layer 1..4 aggregation (128 ch), writes Z = (1+eps)*h + aggr ----------
__global__ void k_agg128(const float* __restrict__ h, const int* __restrict__ rowstart,
                         const int* __restrict__ csr_src, const float* __restrict__ csr_ea,
                         const float* __restrict__ ew, const float* __restrict__ eb,
                         const float* __restrict__ epsp, int layer, float* __restrict__ Z) {
    int wave = (blockIdx.x * blockDim.x + threadIdx.x) >> 6;
    int lane = threadIdx.x & 63;
    if (wave >= N_NODES) return;
    int n = wave;
    int c = lane * 2;
    float2 w0 = *(const float2*)(ew + 0 * HID + c);
    float2 w1 = *(const float2*)(ew + 1 * HID + c);
    float2 w2 = *(const float2*)(ew + 2 * HID + c);
    float2 bb = *(const float2*)(eb + c);
    float accx = 0.f, accy = 0.f;
    int i1 = rowstart[n + 1];
    for (int i = rowstart[n]; i < i1; ++i) {
        int s = csr_src[i];
        float ea0 = csr_ea[3 * i], ea1 = csr_ea[3 * i + 1], ea2 = csr_ea[3 * i + 2];
        float2 hs = *(const float2*)(h + (size_t)s * HID + c);
        float mx = hs.x + ea0 * w0.x + ea1 * w1.x + ea2 * w2.x + bb.x;
        float my = hs.y + ea0 * w0.y + ea1 * w1.y + ea2 * w2.y + bb.y;
        accx += fmaxf(mx, 0.f);
        accy += fmaxf(my, 0.f);
    }
    float epsv = 1.0f + epsp[layer];
    float2 hn = *(const float2*)(h + (size_t)n * HID + c);
    float2 z;
    z.x = epsv * hn.x + accx;
    z.y = epsv * hn.y + accy;
    *(float2*)(Z + (size_t)n * HID + c) = z;
}

// ---------------- fused 2-stage node MLP: Hpre = relu(Z@W1+b1)@W2+b2, + BN stats ------
// 64-row tile per block, 256 threads, 4x8 micro-tile per thread. W read from global (L1-hot).
template <int K1>
__global__ __launch_bounds__(256, 2) void k_mlp(const float* Zin,
                                                const float* __restrict__ W1,
                                                const float* __restrict__ B1,
                                                const float* __restrict__ W2,
                                                const float* __restrict__ B2,
                                                float* Hpre, float* __restrict__ stats) {
    constexpr int BM = 64;
    constexpr int ZS = (K1 == 128) ? 132 : 12;
    __shared__ float zs[BM * ZS];
    __shared__ float ts[BM * 132];
    const int tid = threadIdx.x;
    const int row0 = blockIdx.x * BM;
    const int tc = tid & 15, tr = tid >> 4;
    const int c0 = tc * 8, r0 = tr * 4;

    // ---- stage Z tile into LDS ----
    if (K1 == 128) {
#pragma unroll
        for (int j = 0; j < 8; ++j) {
            int f4 = j * 256 + tid;
            int r = f4 >> 5, k4 = (f4 & 31) << 2;
            float4 v = {0.f, 0.f, 0.f, 0.f};
            if (row0 + r < N_NODES) v = *(const float4*)(Zin + (size_t)(row0 + r) * 128 + k4);
            *(float4*)(zs + r * ZS + k4) = v;
        }
    } else {
        for (int idx = tid; idx < BM * K1; idx += 256) {
            int r = idx / K1, k = idx - r * K1;
            float v = 0.f;
            if (row0 + r < N_NODES) v = Zin[(size_t)(row0 + r) * K1 + k];
            zs[r * ZS + k] = v;
        }
    }
    __syncthreads();

    float b1v[8], b2v[8];
    *(float4*)(b1v) = *(const float4*)(B1 + c0);
    *(float4*)(b1v + 4) = *(const float4*)(B1 + c0 + 4);
    *(float4*)(b2v) = *(const float4*)(B2 + c0);
    *(float4*)(b2v + 4) = *(const float4*)(B2 + c0 + 4);

    // ---- stage 1: t = relu(Z @ W1 + b1) ----
    float acc[4][8];
#pragma unroll
    for (int i = 0; i < 4; ++i)
#pragma unroll
        for (int j = 0; j < 8; ++j) acc[i][j] = 0.f;

#pragma unroll 4
    for (int k = 0; k < K1; ++k) {
        float4 wa = *(const float4*)(W1 + k * 128 + c0);
        float4 wb = *(const float4*)(W1 + k * 128 + c0 + 4);
        float za[4];
#pragma unroll
        for (int i = 0; i < 4; ++i) za[i] = zs[(r0 + i) * ZS + k];
#pragma unroll
        for (int i = 0; i < 4; ++i) {
            acc[i][0] = fmaf(za[i], wa.x, acc[i][0]);
            acc[i][1] = fmaf(za[i], wa.y, acc[i][1]);
            acc[i][2] = fmaf(za[i], wa.z, acc[i][2]);
            acc[i][3] = fmaf(za[i], wa.w, acc[i][3]);
            acc[i][4] = fmaf(za[i], wb.x, acc[i][4]);
            acc[i][5] = fmaf(za[i], wb.y, acc[i][5]);
            acc[i][6] = fmaf(za[i], wb.z, acc[i][6]);
            acc[i][7] = fmaf(za[i], wb.w, acc[i][7]);
        }
    }
#pragma unroll
    for (int i = 0; i < 4; ++i) {
        float4 t0, t1;
        t0.x = fmaxf(acc[i][0] + b1v[0], 0.f);
        t0.y = fmaxf(acc[i][1] + b1v[1], 0.f);
        t0.z = fmaxf(acc[i][2] + b1v[2], 0.f);
        t0.w = fmaxf(acc[i][3] + b1v[3], 0.f);
        t1.x = fmaxf(acc[i][4] + b1v[4], 0.f);
        t1.y = fmaxf(acc[i][5] + b1v[5], 0.f);
        t1.z = fmaxf(acc[i][6] + b1v[6], 0.f);
        t1.w = fmaxf(acc[i][7] + b1v[7], 0.f);
        *(float4*)(ts + (r0 + i) * 132 + c0) = t0;
        *(float4*)(ts + (r0 + i) * 132 + c0 + 4) = t1;
    }
    __syncthreads();

    // ---- stage 2: out = t @ W2 + b2 ----
    float acc2[4][8];
#pragma unroll
    for (int i = 0; i < 4; ++i)
#pragma unroll
        for (int j = 0; j < 8; ++j) acc2[i][j] = 0.f;

#pragma unroll 4
    for (int k = 0; k < 128; ++k) {
        float4 wa = *(const float4*)(W2 + k * 128 + c0);
        float4 wb = *(const float4*)(W2 + k * 128 + c0 + 4);
        float ta[4];
#pragma unroll
        for (int i = 0; i < 4; ++i) ta[i] = ts[(r0 + i) * 132 + k];
#pragma unroll
        for (int i = 0; i < 4; ++i) {
            acc2[i][0] = fmaf(ta[i], wa.x, acc2[i][0]);
            acc2[i][1] = fmaf(ta[i], wa.y, acc2[i][1]);
            acc2[i][2] = fmaf(ta[i], wa.z, acc2[i][2]);
            acc2[i][3] = fmaf(ta[i], wa.w, acc2[i][3]);
            acc2[i][4] = fmaf(ta[i], wb.x, acc2[i][4]);
            acc2[i][5] = fmaf(ta[i], wb.y, acc2[i][5]);
            acc2[i][6] = fmaf(ta[i], wb.z, acc2[i][6]);
            acc2[i][7] = fmaf(ta[i], wb.w, acc2[i][7]);
        }
    }

    // ---- bias add, store, per-thread BN partial stats ----
    float sum[8], ssq[8];
#pragma unroll
    for (int j = 0; j < 8; ++j) { sum[j] = 0.f; ssq[j] = 0.f; }
#pragma unroll
    for (int i = 0; i < 4; ++i) {
        int gr = row0 + r0 + i;
        float o[8];
#pragma unroll
        for (int j = 0; j < 8; ++j) o[j] = acc2[i][j] + b2v[j];
        if (gr < N_NODES) {
            *(float4*)(Hpre + (size_t)gr * 128 + c0) = *(float4*)(o);
            *(float4*)(Hpre + (size_t)gr * 128 + c0 + 4) = *(float4*)(o + 4);
#pragma unroll
            for (int j = 0; j < 8; ++j) {
                sum[j] += o[j];
                ssq[j] += o[j] * o[j];
            }
        }
    }

    // ---- block-reduce stats (reuse ts region: 64*132 >= 4096 floats) ----
    __syncthreads();
    float* red = ts;
#pragma unroll
    for (int j = 0; j < 8; ++j) {
        red[tr * 128 + c0 + j] = sum[j];
        red[2048 + tr * 128 + c0 + j] = ssq[j];
    }
    __syncthreads();
    if (tid < 128) {
        float s = 0.f, q = 0.f;
#pragma unroll
        for (int t = 0; t < 16; ++t) {
            s += red[t * 128 + tid];
            q += red[2048 + t * 128 + tid];
        }
        atomicAdd(&stats[tid], s);
        atomicAdd(&stats[128 + tid], q);
    }
}

// ---------------- BN normalize + relu (+residual), writes h ----------------
__global__ void k_bn(const float* __restrict__ Hpre, const float* __restrict__ stats,
                     const float* __restrict__ gamma, const float* __restrict__ beta,
                     float* __restrict__ h, int residual) {
    int idx = blockIdx.x * 256 + threadIdx.x;   // float4 index into [N,128]
    const float invN = 1.f / (float)N_NODES;
    int c4 = idx & 31;
    float4 v = ((const float4*)Hpre)[idx];
    float4 s0 = ((const float4*)stats)[c4];
    float4 s1 = ((const float4*)(stats + 128))[c4];
    float4 g = ((const float4*)gamma)[c4];
    float4 bt = ((const float4*)beta)[c4];
    float4 r;
    {
        float mu = s0.x * invN, var = s1.x * invN - mu * mu;
        r.x = fmaxf((v.x - mu) * rsqrtf(var + BN_EPS) * g.x + bt.x, 0.f);
    }
    {
        float mu = s0.y * invN, var = s1.y * invN - mu * mu;
        r.y = fmaxf((v.y - mu) * rsqrtf(var + BN_EPS) * g.y + bt.y, 0.f);
    }
    {
        float mu = s0.z * invN, var = s1.z * invN - mu * mu;
        r.z = fmaxf((v.z - mu) * rsqrtf(var + BN_EPS) * g.z + bt.z, 0.f);
    }
    {
        float mu = s0.w * invN, var = s1.w * invN - mu * mu;
        r.w = fmaxf((v.w - mu) * rsqrtf(var + BN_EPS) * g.w + bt.w, 0.f);
    }
    if (residual) {
        float4 hv = ((const float4*)h)[idx];
        r.x += hv.x; r.y += hv.y; r.z += hv.z; r.w += hv.w;
    }
    ((float4*)h)[idx] = r;
}

// ---------------- graph boundaries (batch is sorted) ----------------
__global__ void k_bounds(const int* __restrict__ batch, int* __restrict__ gstart,
                         int* __restrict__ gend) {
    int r = blockIdx.x * 256 + threadIdx.x;
    if (r >= N_NODES) return;
    int b = batch[r];
    if (r == 0 || batch[r - 1] != b) gstart[b] = r;
    if (r == N_NODES - 1 || batch[r + 1] != b) gend[b] = r + 1;
}

// ---------------- mean pool per graph (wave per graph) ----------------
__global__ void k_pool(const float* __restrict__ h, const int* __restrict__ gstart,
                       const int* __restrict__ gend, float* __restrict__ pooled) {
    int wave = (blockIdx.x * blockDim.x + threadIdx.x) >> 6;
    int lane = threadIdx.x & 63;
    if (wave >= N_GRAPHS) return;
    int g = wave;
    int c = lane * 2;
    int a = gstart[g], b = gend[g];
    float ax = 0.f, ay = 0.f;
    for (int r = a; r < b; ++r) {
        float2 v = *(const float2*)(h + (size_t)r * HID + c);
        ax += v.x;
        ay += v.y;
    }
    float d = fmaxf((float)(b - a), 1.f);
    float2 o;
    o.x = ax / d;
    o.y = ay / d;
    *(float2*)(pooled + (size_t)g * HID + c) = o;
}

// ---------------- head MLP: out = relu(relu(p@hw1+hb1)@hw2+hb2)@hw3+hb3 ----------------
__global__ void k_head(const float* __restrict__ pooled, const float* __restrict__ hw1,
                       const float* __restrict__ hb1, const float* __restrict__ hw2,
                       const float* __restrict__ hb2, const float* __restrict__ hw3,
                       const float* __restrict__ hb3, float* __restrict__ out) {
    __shared__ float ps[2][128];
    __shared__ float t1s[2][128];
    __shared__ float red[256];
    int tid = threadIdx.x;
    int rr = tid >> 7, c = tid & 127;
    int row = blockIdx.x * 2 + rr;
    ps[rr][c] = pooled[(size_t)row * 128 + c];
    __syncthreads();
    float a = hb1[c];
    for (int k = 0; k < 128; ++k) a = fmaf(ps[rr][k], hw1[k * 128 + c], a);
    t1s[rr][c] = fmaxf(a, 0.f);
    __syncthreads();
    float b = hb2[c];
    for (int k = 0; k < 128; ++k) b = fmaf(t1s[rr][k], hw2[k * 128 + c], b);
    b = fmaxf(b, 0.f);
    red[tid] = b * hw3[c];
    for (int s = 64; s > 0; s >>= 1) {
        __syncthreads();
        if (c < s) red[tid] += red[tid + s];
    }
    __syncthreads();
    if (c == 0) out[row] = red[tid] + hb3[0];
}

// ---------------- launch ----------------
extern "C" void kernel_launch(void* const* d_in, const int* in_sizes, int n_in,
                              void* d_out, int out_size, void* d_ws, size_t ws_size,
                              hipStream_t stream) {
    const float* x = (const float*)d_in[0];
    const float* edge_attr = (const float*)d_in[1];
    const float* e_w0 = (const float*)d_in[2];
    const float* e_b0 = (const float*)d_in[3];
    const float* w1_0 = (const float*)d_in[4];
    const float* b1_0 = (const float*)d_in[5];
    const float* w2_0 = (const float*)d_in[6];
    const float* b2_0 = (const float*)d_in[7];
    const float* gamma0 = (const float*)d_in[8];
    const float* beta0 = (const float*)d_in[9];
    const float* eps0 = (const float*)d_in[10];
    const float* e_w = (const float*)d_in[11];
    const float* e_b = (const float*)d_in[12];
    const float* w1 = (const float*)d_in[13];
    const float* b1 = (const float*)d_in[14];
    const float* w2 = (const float*)d_in[15];
    const float* b2 = (const float*)d_in[16];
    const float* gamma = (const float*)d_in[17];
    const float* beta = (const float*)d_in[18];
    const float* eps_r = (const float*)d_in[19];
    const float* hw1 = (const float*)d_in[20];
    const float* hb1 = (const float*)d_in[21];
    const float* hw2 = (const float*)d_in[22];
    const float* hb2 = (const float*)d_in[23];
    const float* hw3 = (const float*)d_in[24];
    const float* hb3 = (const float*)d_in[25];
    const int* edge_index = (const int*)d_in[26];
    const int* batch = (const int*)d_in[27];
    float* out = (float*)d_out;

    // workspace layout
    float* wsf = (float*)d_ws;
    size_t off = 0;
    float* A = wsf + off;      off += (size_t)N_NODES * HID;   // h
    float* ZB = wsf + off;     off += (size_t)N_NODES * HID;   // Z / hpre (aliased per-tile)
    float* Z0 = wsf + off;     off += (size_t)N_NODES * IN_DIM;
    float* pooled = wsf + off; off += (size_t)N_GRAPHS * HID;
    float* stats = wsf + off;  off += 5 * 2 * HID;
    float* csr_ea = wsf + off; off += (size_t)3 * N_EDGES;
    int* ib = (int*)(wsf + off);
    size_t io = 0;
    int* deg = ib + io;      io += N_NODES;
    int* rowstart = ib + io; io += N_NODES + 4;
    int* cur = ib + io;      io += N_NODES;
    int* csr_src = ib + io;  io += N_EDGES;
    int* gstart = ib + io;   io += N_GRAPHS;
    int* gend = ib + io;     io += N_GRAPHS;
    int* bsum = ib + io;     io += 512;
    int* boff = ib + io;     io += 512;

    const int EB = (N_EDGES + 255) / 256;        // 2344
    const int NB = (N_NODES + 255) / 256;        // 391
    const int MLPB = (N_NODES + 63) / 64;        // 1563

    // zero control buffers (ws is poisoned before every call)
    k_zero<<<NB, 256, 0, stream>>>(deg, gstart, gend, stats);

    // CSR build
    k_deg<<<EB, 256, 0, stream>>>(edge_index, deg);
    k_scan_a<<<NBLK, SCAN_BS, 0, stream>>>(deg, rowstart, bsum);
    k_scan_b<<<1, 512, 0, stream>>>(bsum, boff);
    k_scan_c<<<NB, 256, 0, stream>>>(rowstart, boff, cur);
    k_fill<<<EB, 256, 0, stream>>>(edge_index, edge_attr, cur, csr_src, csr_ea);

    // layer 0
    k_agg0<<<(N_NODES * 64) / 256, 256, 0, stream>>>(x, rowstart, csr_src, csr_ea, e_w0,
                                                     e_b0, eps0, Z0);
    k_mlp<IN_DIM><<<MLPB, 256, 0, stream>>>(Z0, w1_0, b1_0, w2_0, b2_0, ZB, stats);
    k_bn<<<(N_NODES * HID / 4) / 256, 256, 0, stream>>>(ZB, stats, gamma0, beta0, A, 0);

    // layers 1..4
    for (int i = 0; i < NREST; ++i) {
        k_agg128<<<(N_NODES * 64) / 256, 256, 0, stream>>>(
            A, rowstart, csr_src, csr_ea, e_w + (size_t)i * 3 * HID, e_b + (size_t)i * HID,
            eps_r, i, ZB);
        k_mlp<HID><<<MLPB, 256, 0, stream>>>(ZB, w1 + (size_t)i * HID * HID,
                                             b1 + (size_t)i * HID,
                                             w2 + (size_t)i * HID * HID,
                                             b2 + (size_t)i * HID, ZB,
                                             stats + (size_t)(i + 1) * 2 * HID);
        k_bn<<<(N_NODES * HID / 4) / 256, 256, 0, stream>>>(
            ZB, stats + (size_t)(i + 1) * 2 * HID, gamma + (size_t)i * HID,
            beta + (size_t)i * HID, A, 1);
    }

    // pooling + head
    k_bounds<<<NB, 256, 0, stream>>>(batch, gstart, gend);
    k_pool<<<(N_GRAPHS * 64) / 256, 256, 0, stream>>>(A, gstart, gend, pooled);
    k_head<<<N_GRAPHS / 2, 256, 0, stream>>>(pooled, hw1, hb1, hw2, hb2, hw3, hb3, out);
}

// Round 2
// 1298.007 us; speedup vs baseline: 1.0612x; 1.0612x over previous
//
#include <hip/hip_runtime.h>

#define N_NODES 100000
#define N_EDGES 600000
#define N_GRAPHS 5000
#define IN_DIM 11
#define HID 128
#define NREST 4
#define BN_EPS 1e-5f
#define SCAN_BS 256
#define NBLK ((N_NODES + SCAN_BS - 1) / SCAN_BS)   // 391

// ---------------- utility: zero the small control buffers ----------------
__global__ void k_zero(int* deg, int* gstart, int* gend, float* stats) {
    int i = blockIdx.x * 256 + threadIdx.x;
    if (i < N_NODES) deg[i] = 0;
    if (i < N_GRAPHS) { gstart[i] = 0; gend[i] = 0; }
    if (i < 5 * 2 * HID) stats[i] = 0.f;
}

// ---------------- CSR build (by dst) ----------------
__global__ void k_deg(const int* __restrict__ ei, int* __restrict__ deg) {
    int e = blockIdx.x * 256 + threadIdx.x;
    if (e < N_EDGES) atomicAdd(&deg[ei[N_EDGES + e]], 1);
}

__global__ void k_scan_a(const int* __restrict__ deg, int* __restrict__ rowstart,
                         int* __restrict__ bsum) {
    __shared__ int sh[SCAN_BS];
    int t = threadIdx.x, i = blockIdx.x * SCAN_BS + t;
    int v = (i < N_NODES) ? deg[i] : 0;
    sh[t] = v;
    __syncthreads();
    for (int off = 1; off < SCAN_BS; off <<= 1) {
        int add = (t >= off) ? sh[t - off] : 0;
        __syncthreads();
        sh[t] += add;
        __syncthreads();
    }
    if (i < N_NODES) rowstart[i] = sh[t] - v;           // exclusive (block-local)
    if (t == SCAN_BS - 1) bsum[blockIdx.x] = sh[t];
}

__global__ void k_scan_b(const int* __restrict__ bsum, int* __restrict__ boff) {
    __shared__ int sh[512];
    int t = threadIdx.x;
    int v = (t < NBLK) ? bsum[t] : 0;
    sh[t] = v;
    __syncthreads();
    for (int off = 1; off < 512; off <<= 1) {
        int add = (t >= off) ? sh[t - off] : 0;
        __syncthreads();
        sh[t] += add;
        __syncthreads();
    }
    if (t < NBLK) boff[t] = sh[t] - v;                  // exclusive
}

__global__ void k_scan_c(int* __restrict__ rowstart, const int* __restrict__ boff,
                         int* __restrict__ cur) {
    int i = blockIdx.x * 256 + threadIdx.x;
    if (i < N_NODES) {
        int v = rowstart[i] + boff[i / SCAN_BS];
        rowstart[i] = v;
        cur[i] = v;
    }
    if (i == 0) rowstart[N_NODES] = N_EDGES;
}

__global__ void k_fill(const int* __restrict__ ei, const float* __restrict__ ea,
                       int* __restrict__ cur, int* __restrict__ csr_src,
                       float* __restrict__ csr_ea) {
    int e = blockIdx.x * 256 + threadIdx.x;
    if (e < N_EDGES) {
        int d = ei[N_EDGES + e];
        int p = atomicAdd(&cur[d], 1);
        csr_src[p] = ei[e];
        csr_ea[3 * p + 0] = ea[3 * e + 0];
        csr_ea[3 * p + 1] = ea[3 * e + 1];
        csr_ea[3 * p + 2] = ea[3 * e + 2];
    }
}

// ---------------- layer-0 aggregation (11 channels), writes Z0 = (1+eps)*x + aggr ----------
__global__ void k_agg0(const float* __restrict__ x, const int* __restrict__ rowstart,
                       const int* __restrict__ csr_src, const float* __restrict__ csr_ea,
                       const float* __restrict__ ew, const float* __restrict__ eb,
                       const float* __restrict__ epsp, float* __restrict__ Z0) {
    int wave = (blockIdx.x * blockDim.x + threadIdx.x) >> 6;
    int lane = threadIdx.x & 63;
    if (wave >= N_NODES) return;
    int n = wave;
    if (lane >= IN_DIM) return;
    int c = lane;
    float w0 = ew[0 * IN_DIM + c], w1 = ew[1 * IN_DIM + c], w2 = ew[2 * IN_DIM + c];
    float bb = eb[c];
    float acc = 0.f;
    int i1 = rowstart[n + 1];
    for (int i = rowstart[n]; i < i1; ++i) {
        int s = csr_src[i];
        float ea0 = csr_ea[3 * i], ea1 = csr_ea[3 * i + 1], ea2 = csr_ea[3 * i + 2];
        float m = x[s * IN_DIM + c] + ea0 * w0 + ea1 * w1 + ea2 * w2 + bb;
        acc += fmaxf(m, 0.f);
    }
    float epsv = 1.0f + epsp[0];
    Z0[n * IN_DIM + c] = epsv * x[n * IN_DIM + c] + acc;
}

// ---------------- layer 1..4 aggregation (128 ch), writes Z = (1+eps)*h + aggr ----------
__global__ void k_agg128(const float* __restrict__ h, const int* __restrict__ rowstart,
                         const int* __restrict__ csr_src, const float* __restrict__ csr_ea,
                         const float* __restrict__ ew, const float* __restrict__ eb,
                         const float* __restrict__ epsp, int layer, float* __restrict__ Z) {
    int wave = (blockIdx.x * blockDim.x + threadIdx.x) >> 6;
    int lane = threadIdx.x & 63;
    if (wave >= N_NODES) return;
    int n = wave;
    int c = lane * 2;
    float2 w0 = *(const float2*)(ew + 0 * HID + c);
    float2 w1 = *(const float2*)(ew + 1 * HID + c);
    float2 w2 = *(const float2*)(ew + 2 * HID + c);
    float2 bb = *(const float2*)(eb + c);
    float accx = 0.f, accy = 0.f;
    int i1 = rowstart[n + 1];
    for (int i = rowstart[n]; i < i1; ++i) {
        int s = csr_src[i];
        float ea0 = csr_ea[3 * i], ea1 = csr_ea[3 * i + 1], ea2 = csr_ea[3 * i + 2];
        float2 hs = *(const float2*)(h + (size_t)s * HID + c);
        float mx = hs.x + ea0 * w0.x + ea1 * w1.x + ea2 * w2.x + bb.x;
        float my = hs.y + ea0 * w0.y + ea1 * w1.y + ea2 * w2.y + bb.y;
        accx += fmaxf(mx, 0.f);
        accy += fmaxf(my, 0.f);
    }
    float epsv = 1.0f + epsp[layer];
    float2 hn = *(const float2*)(h + (size_t)n * HID + c);
    float2 z;
    z.x = epsv * hn.x + accx;
    z.y = epsv * hn.y + accy;
    *(float2*)(Z + (size_t)n * HID + c) = z;
}

// ---------------- fused 2-stage node MLP: Hpre = relu(Z@W1+b1)@W2+b2, + BN stats ------
// 64-row tile per block, 256 threads, 4x8 micro-tile per thread. W read from global (L2-hot).
// LDS: single 64x132 buffer, reused for Z tile (stage 1) then T tile (stage 2) -> 33 KB
// -> 4 blocks/CU (was 2 with separate buffers; occupancy was the round-1 limiter).
template <int K1>
__global__ __launch_bounds__(256, 4) void k_mlp(const float* Zin,
                                                const float* __restrict__ W1,
                                                const float* __restrict__ B1,
                                                const float* __restrict__ W2,
                                                const float* __restrict__ B2,
                                                float* Hpre, float* __restrict__ stats) {
    constexpr int BM = 64;
    constexpr int ZS = (K1 == 128) ? 132 : 12;
    __shared__ float sh[BM * 132];                     // 33792 B, Z then T
    const int tid = threadIdx.x;
    const int row0 = blockIdx.x * BM;
    const int tc = tid & 15, tr = tid >> 4;
    const int c0 = tc * 8, r0 = tr * 4;

    // ---- stage Z tile into LDS ----
    if (K1 == 128) {
#pragma unroll
        for (int j = 0; j < 8; ++j) {
            int f4 = j * 256 + tid;
            int r = f4 >> 5, k4 = (f4 & 31) << 2;
            float4 v = {0.f, 0.f, 0.f, 0.f};
            if (row0 + r < N_NODES) v = *(const float4*)(Zin + (size_t)(row0 + r) * 128 + k4);
            *(float4*)(sh + r * ZS + k4) = v;
        }
    } else {
        for (int idx = tid; idx < BM * K1; idx += 256) {
            int r = idx / K1, k = idx - r * K1;
            float v = 0.f;
            if (row0 + r < N_NODES) v = Zin[(size_t)(row0 + r) * K1 + k];
            sh[r * ZS + k] = v;
        }
    }
    __syncthreads();

    float b1v[8], b2v[8];
    *(float4*)(b1v) = *(const float4*)(B1 + c0);
    *(float4*)(b1v + 4) = *(const float4*)(B1 + c0 + 4);
    *(float4*)(b2v) = *(const float4*)(B2 + c0);
    *(float4*)(b2v + 4) = *(const float4*)(B2 + c0 + 4);

    // ---- stage 1: t = relu(Z @ W1 + b1) ----
    float acc[4][8];
#pragma unroll
    for (int i = 0; i < 4; ++i)
#pragma unroll
        for (int j = 0; j < 8; ++j) acc[i][j] = 0.f;

#pragma unroll 4
    for (int k = 0; k < K1; ++k) {
        float4 wa = *(const float4*)(W1 + k * 128 + c0);
        float4 wb = *(const float4*)(W1 + k * 128 + c0 + 4);
        float za[4];
#pragma unroll
        for (int i = 0; i < 4; ++i) za[i] = sh[(r0 + i) * ZS + k];
#pragma unroll
        for (int i = 0; i < 4; ++i) {
            acc[i][0] = fmaf(za[i], wa.x, acc[i][0]);
            acc[i][1] = fmaf(za[i], wa.y, acc[i][1]);
            acc[i][2] = fmaf(za[i], wa.z, acc[i][2]);
            acc[i][3] = fmaf(za[i], wa.w, acc[i][3]);
            acc[i][4] = fmaf(za[i], wb.x, acc[i][4]);
            acc[i][5] = fmaf(za[i], wb.y, acc[i][5]);
            acc[i][6] = fmaf(za[i], wb.z, acc[i][6]);
            acc[i][7] = fmaf(za[i], wb.w, acc[i][7]);
        }
    }

    // all stage-1 LDS reads are done; reuse the buffer for T
    __syncthreads();
#pragma unroll
    for (int i = 0; i < 4; ++i) {
        float4 t0, t1;
        t0.x = fmaxf(acc[i][0] + b1v[0], 0.f);
        t0.y = fmaxf(acc[i][1] + b1v[1], 0.f);
        t0.z = fmaxf(acc[i][2] + b1v[2], 0.f);
        t0.w = fmaxf(acc[i][3] + b1v[3], 0.f);
        t1.x = fmaxf(acc[i][4] + b1v[4], 0.f);
        t1.y = fmaxf(acc[i][5] + b1v[5], 0.f);
        t1.z = fmaxf(acc[i][6] + b1v[6], 0.f);
        t1.w = fmaxf(acc[i][7] + b1v[7], 0.f);
        *(float4*)(sh + (r0 + i) * 132 + c0) = t0;
        *(float4*)(sh + (r0 + i) * 132 + c0 + 4) = t1;
    }
    __syncthreads();

    // ---- stage 2: out = t @ W2 + b2 ----
    float acc2[4][8];
#pragma unroll
    for (int i = 0; i < 4; ++i)
#pragma unroll
        for (int j = 0; j < 8; ++j) acc2[i][j] = 0.f;

#pragma unroll 4
    for (int k = 0; k < 128; ++k) {
        float4 wa = *(const float4*)(W2 + k * 128 + c0);
        float4 wb = *(const float4*)(W2 + k * 128 + c0 + 4);
        float ta[4];
#pragma unroll
        for (int i = 0; i < 4; ++i) ta[i] = sh[(r0 + i) * 132 + k];
#pragma unroll
        for (int i = 0; i < 4; ++i) {
            acc2[i][0] = fmaf(ta[i], wa.x, acc2[i][0]);
            acc2[i][1] = fmaf(ta[i], wa.y, acc2[i][1]);
            acc2[i][2] = fmaf(ta[i], wa.z, acc2[i][2]);
            acc2[i][3] = fmaf(ta[i], wa.w, acc2[i][3]);
            acc2[i][4] = fmaf(ta[i], wb.x, acc2[i][4]);
            acc2[i][5] = fmaf(ta[i], wb.y, acc2[i][5]);
            acc2[i][6] = fmaf(ta[i], wb.z, acc2[i][6]);
            acc2[i][7] = fmaf(ta[i], wb.w, acc2[i][7]);
        }
    }

    // ---- bias add, store, per-thread BN partial stats ----
    float sum[8], ssq[8];
#pragma unroll
    for (int j = 0; j < 8; ++j) { sum[j] = 0.f; ssq[j] = 0.f; }
#pragma unroll
    for (int i = 0; i < 4; ++i) {
        int gr = row0 + r0 + i;
        float o[8];
#pragma unroll
        for (int j = 0; j < 8; ++j) o[j] = acc2[i][j] + b2v[j];
        if (gr < N_NODES) {
            *(float4*)(Hpre + (size_t)gr * 128 + c0) = *(float4*)(o);
            *(float4*)(Hpre + (size_t)gr * 128 + c0 + 4) = *(float4*)(o + 4);
#pragma unroll
            for (int j = 0; j < 8; ++j) {
                sum[j] += o[j];
                ssq[j] += o[j] * o[j];
            }
        }
    }

    // ---- block-reduce stats (reuse sh: need 4096 floats <= 8448) ----
    __syncthreads();
    float* red = sh;
#pragma unroll
    for (int j = 0; j < 8; ++j) {
        red[tr * 128 + c0 + j] = sum[j];
        red[2048 + tr * 128 + c0 + j] = ssq[j];
    }
    __syncthreads();
    if (tid < 128) {
        float s = 0.f, q = 0.f;
#pragma unroll
        for (int t = 0; t < 16; ++t) {
            s += red[t * 128 + tid];
            q += red[2048 + t * 128 + tid];
        }
        atomicAdd(&stats[tid], s);
        atomicAdd(&stats[128 + tid], q);
    }
}

// ---------------- BN normalize + relu (+residual), writes h ----------------
__global__ void k_bn(const float* __restrict__ Hpre, const float* __restrict__ stats,
                     const float* __restrict__ gamma, const float* __restrict__ beta,
                     float* __restrict__ h, int residual) {
    int idx = blockIdx.x * 256 + threadIdx.x;   // float4 index into [N,128]
    const float invN = 1.f / (float)N_NODES;
    int c4 = idx & 31;
    float4 v = ((const float4*)Hpre)[idx];
    float4 s0 = ((const float4*)stats)[c4];
    float4 s1 = ((const float4*)(stats + 128))[c4];
    float4 g = ((const float4*)gamma)[c4];
    float4 bt = ((const float4*)beta)[c4];
    float4 r;
    {
        float mu = s0.x * invN, var = s1.x * invN - mu * mu;
        r.x = fmaxf((v.x - mu) * rsqrtf(var + BN_EPS) * g.x + bt.x, 0.f);
    }
    {
        float mu = s0.y * invN, var = s1.y * invN - mu * mu;
        r.y = fmaxf((v.y - mu) * rsqrtf(var + BN_EPS) * g.y + bt.y, 0.f);
    }
    {
        float mu = s0.z * invN, var = s1.z * invN - mu * mu;
        r.z = fmaxf((v.z - mu) * rsqrtf(var + BN_EPS) * g.z + bt.z, 0.f);
    }
    {
        float mu = s0.w * invN, var = s1.w * invN - mu * mu;
        r.w = fmaxf((v.w - mu) * rsqrtf(var + BN_EPS) * g.w + bt.w, 0.f);
    }
    if (residual) {
        float4 hv = ((const float4*)h)[idx];
        r.x += hv.x; r.y += hv.y; r.z += hv.z; r.w += hv.w;
    }
    ((float4*)h)[idx] = r;
}

// ---------------- graph boundaries (batch is sorted) ----------------
__global__ void k_bounds(const int* __restrict__ batch, int* __restrict__ gstart,
                         int* __restrict__ gend) {
    int r = blockIdx.x * 256 + threadIdx.x;
    if (r >= N_NODES) return;
    int b = batch[r];
    if (r == 0 || batch[r - 1] != b) gstart[b] = r;
    if (r == N_NODES - 1 || batch[r + 1] != b) gend[b] = r + 1;
}

// ---------------- mean pool per graph (wave per graph) ----------------
__global__ void k_pool(const float* __restrict__ h, const int* __restrict__ gstart,
                       const int* __restrict__ gend, float* __restrict__ pooled) {
    int wave = (blockIdx.x * blockDim.x + threadIdx.x) >> 6;
    int lane = threadIdx.x & 63;
    if (wave >= N_GRAPHS) return;
    int g = wave;
    int c = lane * 2;
    int a = gstart[g], b = gend[g];
    float ax = 0.f, ay = 0.f;
    for (int r = a; r < b; ++r) {
        float2 v = *(const float2*)(h + (size_t)r * HID + c);
        ax += v.x;
        ay += v.y;
    }
    float d = fmaxf((float)(b - a), 1.f);
    float2 o;
    o.x = ax / d;
    o.y = ay / d;
    *(float2*)(pooled + (size_t)g * HID + c) = o;
}

// ---------------- head MLP: out = relu(relu(p@hw1+hb1)@hw2+hb2)@hw3+hb3 ----------------
__global__ void k_head(const float* __restrict__ pooled, const float* __restrict__ hw1,
                       const float* __restrict__ hb1, const float* __restrict__ hw2,
                       const float* __restrict__ hb2, const float* __restrict__ hw3,
                       const float* __restrict__ hb3, float* __restrict__ out) {
    __shared__ float ps[2][128];
    __shared__ float t1s[2][128];
    __shared__ float red[256];
    int tid = threadIdx.x;
    int rr = tid >> 7, c = tid & 127;
    int row = blockIdx.x * 2 + rr;
    ps[rr][c] = pooled[(size_t)row * 128 + c];
    __syncthreads();
    float a = hb1[c];
    for (int k = 0; k < 128; ++k) a = fmaf(ps[rr][k], hw1[k * 128 + c], a);
    t1s[rr][c] = fmaxf(a, 0.f);
    __syncthreads();
    float b = hb2[c];
    for (int k = 0; k < 128; ++k) b = fmaf(t1s[rr][k], hw2[k * 128 + c], b);
    b = fmaxf(b, 0.f);
    red[tid] = b * hw3[c];
    for (int s = 64; s > 0; s >>= 1) {
        __syncthreads();
        if (c < s) red[tid] += red[tid + s];
    }
    __syncthreads();
    if (c == 0) out[row] = red[tid] + hb3[0];
}

// ---------------- launch ----------------
extern "C" void kernel_launch(void* const* d_in, const int* in_sizes, int n_in,
                              void* d_out, int out_size, void* d_ws, size_t ws_size,
                              hipStream_t stream) {
    const float* x = (const float*)d_in[0];
    const float* edge_attr = (const float*)d_in[1];
    const float* e_w0 = (const float*)d_in[2];
    const float* e_b0 = (const float*)d_in[3];
    const float* w1_0 = (const float*)d_in[4];
    const float* b1_0 = (const float*)d_in[5];
    const float* w2_0 = (const float*)d_in[6];
    const float* b2_0 = (const float*)d_in[7];
    const float* gamma0 = (const float*)d_in[8];
    const float* beta0 = (const float*)d_in[9];
    const float* eps0 = (const float*)d_in[10];
    const float* e_w = (const float*)d_in[11];
    const float* e_b = (const float*)d_in[12];
    const float* w1 = (const float*)d_in[13];
    const float* b1 = (const float*)d_in[14];
    const float* w2 = (const float*)d_in[15];
    const float* b2 = (const float*)d_in[16];
    const float* gamma = (const float*)d_in[17];
    const float* beta = (const float*)d_in[18];
    const float* eps_r = (const float*)d_in[19];
    const float* hw1 = (const float*)d_in[20];
    const float* hb1 = (const float*)d_in[21];
    const float* hw2 = (const float*)d_in[22];
    const float* hb2 = (const float*)d_in[23];
    const float* hw3 = (const float*)d_in[24];
    const float* hb3 = (const float*)d_in[25];
    const int* edge_index = (const int*)d_in[26];
    const int* batch = (const int*)d_in[27];
    float* out = (float*)d_out;

    // workspace layout
    float* wsf = (float*)d_ws;
    size_t off = 0;
    float* A = wsf + off;      off += (size_t)N_NODES * HID;   // h
    float* ZB = wsf + off;     off += (size_t)N_NODES * HID;   // Z / hpre (aliased per-tile)
    float* Z0 = wsf + off;     off += (size_t)N_NODES * IN_DIM;
    float* pooled = wsf + off; off += (size_t)N_GRAPHS * HID;
    float* stats = wsf + off;  off += 5 * 2 * HID;
    float* csr_ea = wsf + off; off += (size_t)3 * N_EDGES;
    int* ib = (int*)(wsf + off);
    size_t io = 0;
    int* deg = ib + io;      io += N_NODES;
    int* rowstart = ib + io; io += N_NODES + 4;
    int* cur = ib + io;      io += N_NODES;
    int* csr_src = ib + io;  io += N_EDGES;
    int* gstart = ib + io;   io += N_GRAPHS;
    int* gend = ib + io;     io += N_GRAPHS;
    int* bsum = ib + io;     io += 512;
    int* boff = ib + io;     io += 512;

    const int EB = (N_EDGES + 255) / 256;        // 2344
    const int NB = (N_NODES + 255) / 256;        // 391
    const int MLPB = (N_NODES + 63) / 64;        // 1563

    // zero control buffers (ws is poisoned before every call)
    k_zero<<<NB, 256, 0, stream>>>(deg, gstart, gend, stats);

    // CSR build
    k_deg<<<EB, 256, 0, stream>>>(edge_index, deg);
    k_scan_a<<<NBLK, SCAN_BS, 0, stream>>>(deg, rowstart, bsum);
    k_scan_b<<<1, 512, 0, stream>>>(bsum, boff);
    k_scan_c<<<NB, 256, 0, stream>>>(rowstart, boff, cur);
    k_fill<<<EB, 256, 0, stream>>>(edge_index, edge_attr, cur, csr_src, csr_ea);

    // layer 0
    k_agg0<<<(N_NODES * 64) / 256, 256, 0, stream>>>(x, rowstart, csr_src, csr_ea, e_w0,
                                                     e_b0, eps0, Z0);
    k_mlp<IN_DIM><<<MLPB, 256, 0, stream>>>(Z0, w1_0, b1_0, w2_0, b2_0, ZB, stats);
    k_bn<<<(N_NODES * HID / 4) / 256, 256, 0, stream>>>(ZB, stats, gamma0, beta0, A, 0);

    // layers 1..4
    for (int i = 0; i < NREST; ++i) {
        k_agg128<<<(N_NODES * 64) / 256, 256, 0, stream>>>(
            A, rowstart, csr_src, csr_ea, e_w + (size_t)i * 3 * HID, e_b + (size_t)i * HID,
            eps_r, i, ZB);
        k_mlp<HID><<<MLPB, 256, 0, stream>>>(ZB, w1 + (size_t)i * HID * HID,
                                             b1 + (size_t)i * HID,
                                             w2 + (size_t)i * HID * HID,
                                             b2 + (size_t)i * HID, ZB,
                                             stats + (size_t)(i + 1) * 2 * HID);
        k_bn<<<(N_NODES * HID / 4) / 256, 256, 0, stream>>>(
            ZB, stats + (size_t)(i + 1) * 2 * HID, gamma + (size_t)i * HID,
            beta + (size_t)i * HID, A, 1);
    }

    // pooling + head
    k_bounds<<<NB, 256, 0, stream>>>(batch, gstart, gend);
    k_pool<<<(N_GRAPHS * 64) / 256, 256, 0, stream>>>(A, gstart, gend, pooled);
    k_head<<<N_GRAPHS / 2, 256, 0, stream>>>(pooled, hw1, hb1, hw2, hb2, hw3, hb3, out);
}

// Round 3
// 1027.691 us; speedup vs baseline: 1.3404x; 1.2630x over previous
//
#include <hip/hip_runtime.h>

#define N_NODES 100000
#define N_EDGES 600000
#define N_GRAPHS 5000
#define IN_DIM 11
#define HID 128
#define NREST 4
#define BN_EPS 1e-5f
#define SCAN_BS 256
#define NBLK ((N_NODES + SCAN_BS - 1) / SCAN_BS)   // 391
#define WSLOT 16384                                // ushorts per packed weight slot

typedef __bf16 bf16x8 __attribute__((ext_vector_type(8)));
typedef float f32x4 __attribute__((ext_vector_type(4)));

__device__ inline bf16x8 as_bf16x8(uint4 u) { return __builtin_bit_cast(bf16x8, u); }

// fp32 -> (hi, lo) truncated bf16 pair: x ~= hi + lo with |err| <= 2^-16 |x|
__device__ inline void split_bf16(float x, unsigned short& hi, unsigned short& lo) {
    unsigned int b = __float_as_uint(x);
    hi = (unsigned short)(b >> 16);
    float rem = x - __uint_as_float(b & 0xFFFF0000u);
    lo = (unsigned short)(__float_as_uint(rem) >> 16);
}

__device__ inline uint4 pack8(const unsigned short* h) {
    uint4 u;
    u.x = (unsigned)h[0] | ((unsigned)h[1] << 16);
    u.y = (unsigned)h[2] | ((unsigned)h[3] << 16);
    u.z = (unsigned)h[4] | ((unsigned)h[5] << 16);
    u.w = (unsigned)h[6] | ((unsigned)h[7] << 16);
    return u;
}

// ---------------- utility: zero the small control buffers ----------------
__global__ void k_zero(int* deg, int* gstart, int* gend, float* stats) {
    int i = blockIdx.x * 256 + threadIdx.x;
    if (i < N_NODES) deg[i] = 0;
    if (i < N_GRAPHS) { gstart[i] = 0; gend[i] = 0; }
    if (i < 5 * 2 * HID) stats[i] = 0.f;
}

// ---------------- CSR build (by dst) ----------------
__global__ void k_deg(const int* __restrict__ ei, int* __restrict__ deg) {
    int e = blockIdx.x * 256 + threadIdx.x;
    if (e < N_EDGES) atomicAdd(&deg[ei[N_EDGES + e]], 1);
}

__global__ void k_scan_a(const int* __restrict__ deg, int* __restrict__ rowstart,
                         int* __restrict__ bsum) {
    __shared__ int sh[SCAN_BS];
    int t = threadIdx.x, i = blockIdx.x * SCAN_BS + t;
    int v = (i < N_NODES) ? deg[i] : 0;
    sh[t] = v;
    __syncthreads();
    for (int off = 1; off < SCAN_BS; off <<= 1) {
        int add = (t >= off) ? sh[t - off] : 0;
        __syncthreads();
        sh[t] += add;
        __syncthreads();
    }
    if (i < N_NODES) rowstart[i] = sh[t] - v;
    if (t == SCAN_BS - 1) bsum[blockIdx.x] = sh[t];
}

__global__ void k_scan_b(const int* __restrict__ bsum, int* __restrict__ boff) {
    __shared__ int sh[512];
    int t = threadIdx.x;
    int v = (t < NBLK) ? bsum[t] : 0;
    sh[t] = v;
    __syncthreads();
    for (int off = 1; off < 512; off <<= 1) {
        int add = (t >= off) ? sh[t - off] : 0;
        __syncthreads();
        sh[t] += add;
        __syncthreads();
    }
    if (t < NBLK) boff[t] = sh[t] - v;
}

__global__ void k_scan_c(int* __restrict__ rowstart, const int* __restrict__ boff,
                         int* __restrict__ cur) {
    int i = blockIdx.x * 256 + threadIdx.x;
    if (i < N_NODES) {
        int v = rowstart[i] + boff[i / SCAN_BS];
        rowstart[i] = v;
        cur[i] = v;
    }
    if (i == 0) rowstart[N_NODES] = N_EDGES;
}

__global__ void k_fill(const int* __restrict__ ei, const float* __restrict__ ea,
                       int* __restrict__ cur, int* __restrict__ csr_src,
                       float* __restrict__ csr_ea) {
    int e = blockIdx.x * 256 + threadIdx.x;
    if (e < N_EDGES) {
        int d = ei[N_EDGES + e];
        int p = atomicAdd(&cur[d], 1);
        csr_src[p] = ei[e];
        csr_ea[3 * p + 0] = ea[3 * e + 0];
        csr_ea[3 * p + 1] = ea[3 * e + 1];
        csr_ea[3 * p + 2] = ea[3 * e + 2];
    }
}

// ---------------- weight pre-pack into MFMA B-fragment layout (hi/lo bf16) -------------
// slot: 0=w1_0(K=11), 1=w2_0, 2..5=w1[i], 6..9=w2[i]. Frag layout per (kc,cb):
// lane holds 8 consecutive k at col=cb*16+(lane&15), k=kc*32+8*(lane>>4)+j.
__global__ void k_pack(const float* __restrict__ w1_0, const float* __restrict__ w2_0,
                       const float* __restrict__ w1, const float* __restrict__ w2,
                       unsigned short* __restrict__ Whi, unsigned short* __restrict__ Wlo) {
    int bid = blockIdx.x;              // slot*32 + kc*8 + cb
    int slot = bid >> 5;
    int kc = (bid >> 3) & 3, cb = bid & 7;
    int lane = threadIdx.x;            // 64 threads
    const float* src;
    int K;
    if (slot == 0) { src = w1_0; K = IN_DIM; }
    else if (slot == 1) { src = w2_0; K = HID; }
    else if (slot < 6) { src = w1 + (size_t)(slot - 2) * HID * HID; K = HID; }
    else { src = w2 + (size_t)(slot - 6) * HID * HID; K = HID; }
    int col = cb * 16 + (lane & 15);
    int kbase = kc * 32 + 8 * (lane >> 4);
    unsigned short hi[8], lo[8];
#pragma unroll
    for (int j = 0; j < 8; ++j) {
        int k = kbase + j;
        float v = (k < K) ? src[(size_t)k * HID + col] : 0.f;
        split_bf16(v, hi[j], lo[j]);
    }
    size_t base = ((size_t)bid * 64 + lane) * 8;
    *(uint4*)(Whi + base) = pack8(hi);
    *(uint4*)(Wlo + base) = pack8(lo);
}

// ---------------- layer-0 aggregation (11 channels) ----------
__global__ void k_agg0(const float* __restrict__ x, const int* __restrict__ rowstart,
                       const int* __restrict__ csr_src, const float* __restrict__ csr_ea,
                       const float* __restrict__ ew, const float* __restrict__ eb,
                       const float* __restrict__ epsp, float* __restrict__ Z0) {
    int wave = (blockIdx.x * blockDim.x + threadIdx.x) >> 6;
    int lane = threadIdx.x & 63;
    if (wave >= N_NODES) return;
    int n = wave;
    if (lane >= IN_DIM) return;
    int c = lane;
    float w0 = ew[0 * IN_DIM + c], w1 = ew[1 * IN_DIM + c], w2 = ew[2 * IN_DIM + c];
    float bb = eb[c];
    float acc = 0.f;
    int i1 = rowstart[n + 1];
    for (int i = rowstart[n]; i < i1; ++i) {
        int s = csr_src[i];
        float ea0 = csr_ea[3 * i], ea1 = csr_ea[3 * i + 1], ea2 = csr_ea[3 * i + 2];
        float m = x[s * IN_DIM + c] + ea0 * w0 + ea1 * w1 + ea2 * w2 + bb;
        acc += fmaxf(m, 0.f);
    }
    float epsv = 1.0f + epsp[0];
    Z0[n * IN_DIM + c] = epsv * x[n * IN_DIM + c] + acc;
}

// ---------------- layer 1..4 aggregation (128 ch) ----------
__global__ void k_agg128(const float* __restrict__ h, const int* __restrict__ rowstart,
                         const int* __restrict__ csr_src, const float* __restrict__ csr_ea,
                         const float* __restrict__ ew, const float* __restrict__ eb,
                         const float* __restrict__ epsp, int layer, float* __restrict__ Z) {
    int wave = (blockIdx.x * blockDim.x + threadIdx.x) >> 6;
    int lane = threadIdx.x & 63;
    if (wave >= N_NODES) return;
    int n = wave;
    int c = lane * 2;
    float2 w0 = *(const float2*)(ew + 0 * HID + c);
    float2 w1 = *(const float2*)(ew + 1 * HID + c);
    float2 w2 = *(const float2*)(ew + 2 * HID + c);
    float2 bb = *(const float2*)(eb + c);
    float accx = 0.f, accy = 0.f;
    int i1 = rowstart[n + 1];
    for (int i = rowstart[n]; i < i1; ++i) {
        int s = csr_src[i];
        float ea0 = csr_ea[3 * i], ea1 = csr_ea[3 * i + 1], ea2 = csr_ea[3 * i + 2];
        float2 hs = *(const float2*)(h + (size_t)s * HID + c);
        float mx = hs.x + ea0 * w0.x + ea1 * w1.x + ea2 * w2.x + bb.x;
        float my = hs.y + ea0 * w0.y + ea1 * w1.y + ea2 * w2.y + bb.y;
        accx += fmaxf(mx, 0.f);
        accy += fmaxf(my, 0.f);
    }
    float epsv = 1.0f + epsp[layer];
    float2 hn = *(const float2*)(h + (size_t)n * HID + c);
    float2 z;
    z.x = epsv * hn.x + accx;
    z.y = epsv * hn.y + accy;
    *(float2*)(Z + (size_t)n * HID + c) = z;
}

// ---------------- MFMA node MLP: Hpre = relu(Z@W1+b1)@W2+b2, + BN stats ----------------
// 64 rows/block, 4 waves; wave w owns output cols [32w,32w+32) (colblocks cb=2w,2w+1).
// bf16 hi/lo split, 3 MFMAs per fragment pair (hi*hi + lo*hi + hi*lo), fp32 accum.
template <int K1>
__global__ __launch_bounds__(256, 4) void k_mlp(const float* Zin,
        const unsigned short* __restrict__ W1hi, const unsigned short* __restrict__ W1lo,
        const unsigned short* __restrict__ W2hi, const unsigned short* __restrict__ W2lo,
        const float* __restrict__ B1, const float* __restrict__ B2,
        float* Hpre, float* __restrict__ stats) {
    constexpr int KC1 = (K1 == 128) ? 4 : 1;
    __shared__ __align__(16) unsigned short ahi[4 * 4 * 64 * 8];   // 16 KB (A frags / T frags)
    __shared__ __align__(16) unsigned short alo[4 * 4 * 64 * 8];   // 16 KB
    __shared__ float red[1024];                                    // 4 KB BN partials
    const int tid = threadIdx.x;
    const int w = tid >> 6;          // wave 0..3
    const int l = tid & 63;          // lane
    const int row0 = blockIdx.x * 64;

    // ---- stage Z -> packed A fragments (hi/lo bf16), linear b128 LDS writes ----
    if (K1 == 128) {
#pragma unroll
        for (int it = 0; it < 4; ++it) {
            int s = tid + it * 256;                 // s = ((wr*4+kc)*64+lane)
            int lane = s & 63, kc = (s >> 6) & 3, wr = s >> 8;
            int r = row0 + wr * 16 + (lane & 15);
            int k0 = kc * 32 + 8 * (lane >> 4);
            float v[8];
            if (r < N_NODES) {
                *(float4*)(v) = *(const float4*)(Zin + (size_t)r * 128 + k0);
                *(float4*)(v + 4) = *(const float4*)(Zin + (size_t)r * 128 + k0 + 4);
            } else {
#pragma unroll
                for (int j = 0; j < 8; ++j) v[j] = 0.f;
            }
            unsigned short h[8], q[8];
#pragma unroll
            for (int j = 0; j < 8; ++j) split_bf16(v[j], h[j], q[j]);
            *(uint4*)(ahi + (size_t)s * 8) = pack8(h);
            *(uint4*)(alo + (size_t)s * 8) = pack8(q);
        }
    } else {
        // K1 == 11: only kc=0 fragments exist; 256 slots
        int lane = tid & 63, wr = tid >> 6;
        int r = row0 + wr * 16 + (lane & 15);
        int k0 = 8 * (lane >> 4);
        float v[8];
#pragma unroll
        for (int j = 0; j < 8; ++j) {
            int k = k0 + j;
            v[j] = (r < N_NODES && k < IN_DIM) ? Zin[(size_t)r * IN_DIM + k] : 0.f;
        }
        unsigned short h[8], q[8];
#pragma unroll
        for (int j = 0; j < 8; ++j) split_bf16(v[j], h[j], q[j]);
        size_t s = (size_t)(wr * 4 + 0) * 64 + lane;
        *(uint4*)(ahi + s * 8) = pack8(h);
        *(uint4*)(alo + s * 8) = pack8(q);
    }
    __syncthreads();

    const int cb0 = 2 * w, cb1 = cb0 + 1;
    const f32x4 zf = {0.f, 0.f, 0.f, 0.f};

    // ---- stage 1: T = relu(Z @ W1 + b1) ----
    f32x4 acc[4][2];
#pragma unroll
    for (int wr = 0; wr < 4; ++wr) { acc[wr][0] = zf; acc[wr][1] = zf; }

#pragma unroll
    for (int kc = 0; kc < KC1; ++kc) {
        bf16x8 bh0 = as_bf16x8(*(const uint4*)(W1hi + ((size_t)(kc * 8 + cb0) * 64 + l) * 8));
        bf16x8 bl0 = as_bf16x8(*(const uint4*)(W1lo + ((size_t)(kc * 8 + cb0) * 64 + l) * 8));
        bf16x8 bh1 = as_bf16x8(*(const uint4*)(W1hi + ((size_t)(kc * 8 + cb1) * 64 + l) * 8));
        bf16x8 bl1 = as_bf16x8(*(const uint4*)(W1lo + ((size_t)(kc * 8 + cb1) * 64 + l) * 8));
#pragma unroll
        for (int wr = 0; wr < 4; ++wr) {
            bf16x8 a_h = as_bf16x8(*(const uint4*)(ahi + ((size_t)(wr * 4 + kc) * 64 + l) * 8));
            bf16x8 a_l = as_bf16x8(*(const uint4*)(alo + ((size_t)(wr * 4 + kc) * 64 + l) * 8));
            acc[wr][0] = __builtin_amdgcn_mfma_f32_16x16x32_bf16(a_h, bh0, acc[wr][0], 0, 0, 0);
            acc[wr][1] = __builtin_amdgcn_mfma_f32_16x16x32_bf16(a_h, bh1, acc[wr][1], 0, 0, 0);
            acc[wr][0] = __builtin_amdgcn_mfma_f32_16x16x32_bf16(a_l, bh0, acc[wr][0], 0, 0, 0);
            acc[wr][1] = __builtin_amdgcn_mfma_f32_16x16x32_bf16(a_l, bh1, acc[wr][1], 0, 0, 0);
            acc[wr][0] = __builtin_amdgcn_mfma_f32_16x16x32_bf16(a_h, bl0, acc[wr][0], 0, 0, 0);
            acc[wr][1] = __builtin_amdgcn_mfma_f32_16x16x32_bf16(a_h, bl1, acc[wr][1], 0, 0, 0);
        }
    }
    __syncthreads();   // all stage-1 A reads done; reuse ahi/alo for T

    // ---- bias+relu, repack T into A-fragment layout (this wave produces kc2 = w) ----
    {
        float b1c0 = B1[cb0 * 16 + (l & 15)];
        float b1c1 = B1[cb1 * 16 + (l & 15)];
        int j2 = l & 7;
        int hi16 = (l & 15) >> 3;
        int l2r = (l >> 4) * 4;
#pragma unroll
        for (int wr = 0; wr < 4; ++wr) {
#pragma unroll
            for (int cbl = 0; cbl < 2; ++cbl) {
                float bv = cbl ? b1c1 : b1c0;
                f32x4 v = acc[wr][cbl];
#pragma unroll
                for (int r = 0; r < 4; ++r) {
                    float t = fmaxf(v[r] + bv, 0.f);
                    unsigned short hh, qq;
                    split_bf16(t, hh, qq);
                    int l2 = l2r + r + 16 * (2 * cbl + hi16);
                    int off = ((wr * 4 + w) * 64 + l2) * 8 + j2;
                    ahi[off] = hh;
                    alo[off] = qq;
                }
            }
        }
    }
    __syncthreads();

    // ---- stage 2: out = T @ W2 + b2 ----
    f32x4 acc2[4][2];
#pragma unroll
    for (int wr = 0; wr < 4; ++wr) { acc2[wr][0] = zf; acc2[wr][1] = zf; }

#pragma unroll
    for (int kc = 0; kc < 4; ++kc) {
        bf16x8 bh0 = as_bf16x8(*(const uint4*)(W2hi + ((size_t)(kc * 8 + cb0) * 64 + l) * 8));
        bf16x8 bl0 = as_bf16x8(*(const uint4*)(W2lo + ((size_t)(kc * 8 + cb0) * 64 + l) * 8));
        bf16x8 bh1 = as_bf16x8(*(const uint4*)(W2hi + ((size_t)(kc * 8 + cb1) * 64 + l) * 8));
        bf16x8 bl1 = as_bf16x8(*(const uint4*)(W2lo + ((size_t)(kc * 8 + cb1) * 64 + l) * 8));
#pragma unroll
        for (int wr = 0; wr < 4; ++wr) {
            bf16x8 a_h = as_bf16x8(*(const uint4*)(ahi + ((size_t)(wr * 4 + kc) * 64 + l) * 8));
            bf16x8 a_l = as_bf16x8(*(const uint4*)(alo + ((size_t)(wr * 4 + kc) * 64 + l) * 8));
            acc2[wr][0] = __builtin_amdgcn_mfma_f32_16x16x32_bf16(a_h, bh0, acc2[wr][0], 0, 0, 0);
            acc2[wr][1] = __builtin_amdgcn_mfma_f32_16x16x32_bf16(a_h, bh1, acc2[wr][1], 0, 0, 0);
            acc2[wr][0] = __builtin_amdgcn_mfma_f32_16x16x32_bf16(a_l, bh0, acc2[wr][0], 0, 0, 0);
            acc2[wr][1] = __builtin_amdgcn_mfma_f32_16x16x32_bf16(a_l, bh1, acc2[wr][1], 0, 0, 0);
            acc2[wr][0] = __builtin_amdgcn_mfma_f32_16x16x32_bf16(a_h, bl0, acc2[wr][0], 0, 0, 0);
            acc2[wr][1] = __builtin_amdgcn_mfma_f32_16x16x32_bf16(a_h, bl1, acc2[wr][1], 0, 0, 0);
        }
    }

    // ---- epilogue: bias, store Hpre, BN partial stats ----
    {
        float b2c0 = B2[cb0 * 16 + (l & 15)];
        float b2c1 = B2[cb1 * 16 + (l & 15)];
        float s0 = 0.f, q0 = 0.f, s1 = 0.f, q1 = 0.f;
#pragma unroll
        for (int wr = 0; wr < 4; ++wr) {
#pragma unroll
            for (int r = 0; r < 4; ++r) {
                int grow = row0 + wr * 16 + (l >> 4) * 4 + r;
                if (grow < N_NODES) {
                    float o0 = acc2[wr][0][r] + b2c0;
                    float o1 = acc2[wr][1][r] + b2c1;
                    Hpre[(size_t)grow * 128 + cb0 * 16 + (l & 15)] = o0;
                    Hpre[(size_t)grow * 128 + cb1 * 16 + (l & 15)] = o1;
                    s0 += o0; q0 += o0 * o0;
                    s1 += o1; q1 += o1 * o1;
                }
            }
        }
        red[(w * 2 + 0) * 64 + l] = s0;
        red[(w * 2 + 1) * 64 + l] = s1;
        red[512 + (w * 2 + 0) * 64 + l] = q0;
        red[512 + (w * 2 + 1) * 64 + l] = q1;
    }
    __syncthreads();
    if (tid < 128) {
        // col = tid: w=tid>>5, cbl=(tid>>4)&1, lane&15 = tid&15; contributing lanes l0+16g
        int b = ((tid >> 5) * 2 + ((tid >> 4) & 1)) * 64 + (tid & 15);
        float ss = red[b] + red[b + 16] + red[b + 32] + red[b + 48];
        float qq = red[512 + b] + red[512 + b + 16] + red[512 + b + 32] + red[512 + b + 48];
        atomicAdd(&stats[tid], ss);
        atomicAdd(&stats[128 + tid], qq);
    }
}

// ---------------- BN normalize + relu (+residual), writes h ----------------
__global__ void k_bn(const float* __restrict__ Hpre, const float* __restrict__ stats,
                     const float* __restrict__ gamma, const float* __restrict__ beta,
                     float* __restrict__ h, int residual) {
    int idx = blockIdx.x * 256 + threadIdx.x;   // float4 index into [N,128]
    const float invN = 1.f / (float)N_NODES;
    int c4 = idx & 31;
    float4 v = ((const float4*)Hpre)[idx];
    float4 s0 = ((const float4*)stats)[c4];
    float4 s1 = ((const float4*)(stats + 128))[c4];
    float4 g = ((const float4*)gamma)[c4];
    float4 bt = ((const float4*)beta)[c4];
    float4 r;
    {
        float mu = s0.x * invN, var = s1.x * invN - mu * mu;
        r.x = fmaxf((v.x - mu) * rsqrtf(var + BN_EPS) * g.x + bt.x, 0.f);
    }
    {
        float mu = s0.y * invN, var = s1.y * invN - mu * mu;
        r.y = fmaxf((v.y - mu) * rsqrtf(var + BN_EPS) * g.y + bt.y, 0.f);
    }
    {
        float mu = s0.z * invN, var = s1.z * invN - mu * mu;
        r.z = fmaxf((v.z - mu) * rsqrtf(var + BN_EPS) * g.z + bt.z, 0.f);
    }
    {
        float mu = s0.w * invN, var = s1.w * invN - mu * mu;
        r.w = fmaxf((v.w - mu) * rsqrtf(var + BN_EPS) * g.w + bt.w, 0.f);
    }
    if (residual) {
        float4 hv = ((const float4*)h)[idx];
        r.x += hv.x; r.y += hv.y; r.z += hv.z; r.w += hv.w;
    }
    ((float4*)h)[idx] = r;
}

// ---------------- graph boundaries (batch is sorted) ----------------
__global__ void k_bounds(const int* __restrict__ batch, int* __restrict__ gstart,
                         int* __restrict__ gend) {
    int r = blockIdx.x * 256 + threadIdx.x;
    if (r >= N_NODES) return;
    int b = batch[r];
    if (r == 0 || batch[r - 1] != b) gstart[b] = r;
    if (r == N_NODES - 1 || batch[r + 1] != b) gend[b] = r + 1;
}

// ---------------- mean pool per graph (wave per graph) ----------------
__global__ void k_pool(const float* __restrict__ h, const int* __restrict__ gstart,
                       const int* __restrict__ gend, float* __restrict__ pooled) {
    int wave = (blockIdx.x * blockDim.x + threadIdx.x) >> 6;
    int lane = threadIdx.x & 63;
    if (wave >= N_GRAPHS) return;
    int g = wave;
    int c = lane * 2;
    int a = gstart[g], b = gend[g];
    float ax = 0.f, ay = 0.f;
    for (int r = a; r < b; ++r) {
        float2 v = *(const float2*)(h + (size_t)r * HID + c);
        ax += v.x;
        ay += v.y;
    }
    float d = fmaxf((float)(b - a), 1.f);
    float2 o;
    o.x = ax / d;
    o.y = ay / d;
    *(float2*)(pooled + (size_t)g * HID + c) = o;
}

// ---------------- head MLP ----------------
__global__ void k_head(const float* __restrict__ pooled, const float* __restrict__ hw1,
                       const float* __restrict__ hb1, const float* __restrict__ hw2,
                       const float* __restrict__ hb2, const float* __restrict__ hw3,
                       const float* __restrict__ hb3, float* __restrict__ out) {
    __shared__ float ps[2][128];
    __shared__ float t1s[2][128];
    __shared__ float red[256];
    int tid = threadIdx.x;
    int rr = tid >> 7, c = tid & 127;
    int row = blockIdx.x * 2 + rr;
    ps[rr][c] = pooled[(size_t)row * 128 + c];
    __syncthreads();
    float a = hb1[c];
    for (int k = 0; k < 128; ++k) a = fmaf(ps[rr][k], hw1[k * 128 + c], a);
    t1s[rr][c] = fmaxf(a, 0.f);
    __syncthreads();
    float b = hb2[c];
    for (int k = 0; k < 128; ++k) b = fmaf(t1s[rr][k], hw2[k * 128 + c], b);
    b = fmaxf(b, 0.f);
    red[tid] = b * hw3[c];
    for (int s = 64; s > 0; s >>= 1) {
        __syncthreads();
        if (c < s) red[tid] += red[tid + s];
    }
    __syncthreads();
    if (c == 0) out[row] = red[tid] + hb3[0];
}

// ---------------- launch ----------------
extern "C" void kernel_launch(void* const* d_in, const int* in_sizes, int n_in,
                              void* d_out, int out_size, void* d_ws, size_t ws_size,
                              hipStream_t stream) {
    const float* x = (const float*)d_in[0];
    const float* edge_attr = (const float*)d_in[1];
    const float* e_w0 = (const float*)d_in[2];
    const float* e_b0 = (const float*)d_in[3];
    const float* w1_0 = (const float*)d_in[4];
    const float* b1_0 = (const float*)d_in[5];
    const float* w2_0 = (const float*)d_in[6];
    const float* b2_0 = (const float*)d_in[7];
    const float* gamma0 = (const float*)d_in[8];
    const float* beta0 = (const float*)d_in[9];
    const float* eps0 = (const float*)d_in[10];
    const float* e_w = (const float*)d_in[11];
    const float* e_b = (const float*)d_in[12];
    const float* w1 = (const float*)d_in[13];
    const float* b1 = (const float*)d_in[14];
    const float* w2 = (const float*)d_in[15];
    const float* b2 = (const float*)d_in[16];
    const float* gamma = (const float*)d_in[17];
    const float* beta = (const float*)d_in[18];
    const float* eps_r = (const float*)d_in[19];
    const float* hw1 = (const float*)d_in[20];
    const float* hb1 = (const float*)d_in[21];
    const float* hw2 = (const float*)d_in[22];
    const float* hb2 = (const float*)d_in[23];
    const float* hw3 = (const float*)d_in[24];
    const float* hb3 = (const float*)d_in[25];
    const int* edge_index = (const int*)d_in[26];
    const int* batch = (const int*)d_in[27];
    float* out = (float*)d_out;

    // workspace layout
    float* wsf = (float*)d_ws;
    size_t off = 0;
    float* A = wsf + off;      off += (size_t)N_NODES * HID;   // h
    float* ZB = wsf + off;     off += (size_t)N_NODES * HID;   // Z / hpre (aliased per-tile)
    float* Z0 = wsf + off;     off += (size_t)N_NODES * IN_DIM;
    float* pooled = wsf + off; off += (size_t)N_GRAPHS * HID;
    float* stats = wsf + off;  off += 5 * 2 * HID;
    float* csr_ea = wsf + off; off += (size_t)3 * N_EDGES;
    int* ib = (int*)(wsf + off);
    size_t io = 0;
    int* deg = ib + io;      io += N_NODES;
    int* rowstart = ib + io; io += N_NODES + 4;
    int* cur = ib + io;      io += N_NODES;
    int* csr_src = ib + io;  io += N_EDGES;
    int* gstart = ib + io;   io += N_GRAPHS;
    int* gend = ib + io;     io += N_GRAPHS;
    int* bsum = ib + io;     io += 512;
    int* boff = ib + io;     io += 512;
    unsigned short* Whi = (unsigned short*)(ib + io);          // 10 slots * 16384 ushorts
    unsigned short* Wlo = Whi + 10 * WSLOT;

    const int EB = (N_EDGES + 255) / 256;        // 2344
    const int NB = (N_NODES + 255) / 256;        // 391
    const int MLPB = (N_NODES + 63) / 64;        // 1563

    // zero control buffers + pack weights (ws is poisoned before every call)
    k_zero<<<NB, 256, 0, stream>>>(deg, gstart, gend, stats);
    k_pack<<<320, 64, 0, stream>>>(w1_0, w2_0, w1, w2, Whi, Wlo);

    // CSR build
    k_deg<<<EB, 256, 0, stream>>>(edge_index, deg);
    k_scan_a<<<NBLK, SCAN_BS, 0, stream>>>(deg, rowstart, bsum);
    k_scan_b<<<1, 512, 0, stream>>>(bsum, boff);
    k_scan_c<<<NB, 256, 0, stream>>>(rowstart, boff, cur);
    k_fill<<<EB, 256, 0, stream>>>(edge_index, edge_attr, cur, csr_src, csr_ea);

    // layer 0
    k_agg0<<<(N_NODES * 64) / 256, 256, 0, stream>>>(x, rowstart, csr_src, csr_ea, e_w0,
                                                     e_b0, eps0, Z0);
    k_mlp<IN_DIM><<<MLPB, 256, 0, stream>>>(Z0, Whi + 0 * WSLOT, Wlo + 0 * WSLOT,
                                            Whi + 1 * WSLOT, Wlo + 1 * WSLOT,
                                            b1_0, b2_0, ZB, stats);
    k_bn<<<(N_NODES * HID / 4) / 256, 256, 0, stream>>>(ZB, stats, gamma0, beta0, A, 0);

    // layers 1..4
    for (int i = 0; i < NREST; ++i) {
        k_agg128<<<(N_NODES * 64) / 256, 256, 0, stream>>>(
            A, rowstart, csr_src, csr_ea, e_w + (size_t)i * 3 * HID, e_b + (size_t)i * HID,
            eps_r, i, ZB);
        k_mlp<HID><<<MLPB, 256, 0, stream>>>(ZB, Whi + (size_t)(2 + i) * WSLOT,
                                             Wlo + (size_t)(2 + i) * WSLOT,
                                             Whi + (size_t)(6 + i) * WSLOT,
                                             Wlo + (size_t)(6 + i) * WSLOT,
                                             b1 + (size_t)i * HID, b2 + (size_t)i * HID,
                                             ZB, stats + (size_t)(i + 1) * 2 * HID);
        k_bn<<<(N_NODES * HID / 4) / 256, 256, 0, stream>>>(
            ZB, stats + (size_t)(i + 1) * 2 * HID, gamma + (size_t)i * HID,
            beta + (size_t)i * HID, A, 1);
    }

    // pooling + head
    k_bounds<<<NB, 256, 0, stream>>>(batch, gstart, gend);
    k_pool<<<(N_GRAPHS * 64) / 256, 256, 0, stream>>>(A, gstart, gend, pooled);
    k_head<<<N_GRAPHS / 2, 256, 0, stream>>>(pooled, hw1, hb1, hw2, hb2, hw3, hb3, out);
}

// Round 4
// 943.346 us; speedup vs baseline: 1.4602x; 1.0894x over previous
//
#include <hip/hip_runtime.h>
#include <hip/hip_fp16.h>

#define N_NODES 100000
#define N_EDGES 600000
#define N_GRAPHS 5000
#define IN_DIM 11
#define HID 128
#define NREST 4
#define BN_EPS 1e-5f
#define SCAN_BS 256
#define NBLK ((N_NODES + SCAN_BS - 1) / SCAN_BS)   // 391
#define WSLOT 16384                                // ushorts per packed weight slot

typedef __bf16 bf16x8 __attribute__((ext_vector_type(8)));
typedef float f32x4 __attribute__((ext_vector_type(4)));

__device__ inline bf16x8 as_bf16x8(uint4 u) { return __builtin_bit_cast(bf16x8, u); }

// fp32 -> (hi, lo) truncated bf16 pair: x ~= hi + lo with |err| <= 2^-16 |x|
__device__ inline void split_bf16(float x, unsigned short& hi, unsigned short& lo) {
    unsigned int b = __float_as_uint(x);
    hi = (unsigned short)(b >> 16);
    float rem = x - __uint_as_float(b & 0xFFFF0000u);
    lo = (unsigned short)(__float_as_uint(rem) >> 16);
}

__device__ inline uint4 pack8(const unsigned short* h) {
    uint4 u;
    u.x = (unsigned)h[0] | ((unsigned)h[1] << 16);
    u.y = (unsigned)h[2] | ((unsigned)h[3] << 16);
    u.z = (unsigned)h[4] | ((unsigned)h[5] << 16);
    u.w = (unsigned)h[6] | ((unsigned)h[7] << 16);
    return u;
}

// ---------------- utility: zero the small control buffers ----------------
__global__ void k_zero(int* deg, int* gstart, int* gend, float* stats) {
    int i = blockIdx.x * 256 + threadIdx.x;
    if (i < N_NODES) deg[i] = 0;
    if (i < N_GRAPHS) { gstart[i] = 0; gend[i] = 0; }
    if (i < 5 * 2 * HID) stats[i] = 0.f;
}

// ---------------- CSR build (by dst) ----------------
__global__ void k_deg(const int* __restrict__ ei, int* __restrict__ deg) {
    int e = blockIdx.x * 256 + threadIdx.x;
    if (e < N_EDGES) atomicAdd(&deg[ei[N_EDGES + e]], 1);
}

__global__ void k_scan_a(const int* __restrict__ deg, int* __restrict__ rowstart,
                         int* __restrict__ bsum) {
    __shared__ int sh[SCAN_BS];
    int t = threadIdx.x, i = blockIdx.x * SCAN_BS + t;
    int v = (i < N_NODES) ? deg[i] : 0;
    sh[t] = v;
    __syncthreads();
    for (int off = 1; off < SCAN_BS; off <<= 1) {
        int add = (t >= off) ? sh[t - off] : 0;
        __syncthreads();
        sh[t] += add;
        __syncthreads();
    }
    if (i < N_NODES) rowstart[i] = sh[t] - v;
    if (t == SCAN_BS - 1) bsum[blockIdx.x] = sh[t];
}

__global__ void k_scan_b(const int* __restrict__ bsum, int* __restrict__ boff) {
    __shared__ int sh[512];
    int t = threadIdx.x;
    int v = (t < NBLK) ? bsum[t] : 0;
    sh[t] = v;
    __syncthreads();
    for (int off = 1; off < 512; off <<= 1) {
        int add = (t >= off) ? sh[t - off] : 0;
        __syncthreads();
        sh[t] += add;
        __syncthreads();
    }
    if (t < NBLK) boff[t] = sh[t] - v;
}

__global__ void k_scan_c(int* __restrict__ rowstart, const int* __restrict__ boff,
                         int* __restrict__ cur) {
    int i = blockIdx.x * 256 + threadIdx.x;
    if (i < N_NODES) {
        int v = rowstart[i] + boff[i / SCAN_BS];
        rowstart[i] = v;
        cur[i] = v;
    }
    if (i == 0) rowstart[N_NODES] = N_EDGES;
}

__global__ void k_fill(const int* __restrict__ ei, const float* __restrict__ ea,
                       int* __restrict__ cur, int* __restrict__ csr_src,
                       float* __restrict__ csr_ea) {
    int e = blockIdx.x * 256 + threadIdx.x;
    if (e < N_EDGES) {
        int d = ei[N_EDGES + e];
        int p = atomicAdd(&cur[d], 1);
        csr_src[p] = ei[e];
        csr_ea[3 * p + 0] = ea[3 * e + 0];
        csr_ea[3 * p + 1] = ea[3 * e + 1];
        csr_ea[3 * p + 2] = ea[3 * e + 2];
    }
}

// ---------------- weight pre-pack into MFMA B-fragment layout (hi/lo bf16) -------------
__global__ void k_pack(const float* __restrict__ w1_0, const float* __restrict__ w2_0,
                       const float* __restrict__ w1, const float* __restrict__ w2,
                       unsigned short* __restrict__ Whi, unsigned short* __restrict__ Wlo) {
    int bid = blockIdx.x;              // slot*32 + kc*8 + cb
    int slot = bid >> 5;
    int kc = (bid >> 3) & 3, cb = bid & 7;
    int lane = threadIdx.x;            // 64 threads
    const float* src;
    int K;
    if (slot == 0) { src = w1_0; K = IN_DIM; }
    else if (slot == 1) { src = w2_0; K = HID; }
    else if (slot < 6) { src = w1 + (size_t)(slot - 2) * HID * HID; K = HID; }
    else { src = w2 + (size_t)(slot - 6) * HID * HID; K = HID; }
    int col = cb * 16 + (lane & 15);
    int kbase = kc * 32 + 8 * (lane >> 4);
    unsigned short hi[8], lo[8];
#pragma unroll
    for (int j = 0; j < 8; ++j) {
        int k = kbase + j;
        float v = (k < K) ? src[(size_t)k * HID + col] : 0.f;
        split_bf16(v, hi[j], lo[j]);
    }
    size_t base = ((size_t)bid * 64 + lane) * 8;
    *(uint4*)(Whi + base) = pack8(hi);
    *(uint4*)(Wlo + base) = pack8(lo);
}

// ---------------- layer-0 aggregation (11 channels) ----------
__global__ void k_agg0(const float* __restrict__ x, const int* __restrict__ rowstart,
                       const int* __restrict__ csr_src, const float* __restrict__ csr_ea,
                       const float* __restrict__ ew, const float* __restrict__ eb,
                       const float* __restrict__ epsp, float* __restrict__ Z0) {
    int wave = (blockIdx.x * blockDim.x + threadIdx.x) >> 6;
    int lane = threadIdx.x & 63;
    if (wave >= N_NODES) return;
    int n = wave;
    if (lane >= IN_DIM) return;
    int c = lane;
    float w0 = ew[0 * IN_DIM + c], w1 = ew[1 * IN_DIM + c], w2 = ew[2 * IN_DIM + c];
    float bb = eb[c];
    float acc = 0.f;
    int i1 = rowstart[n + 1];
    for (int i = rowstart[n]; i < i1; ++i) {
        int s = csr_src[i];
        float ea0 = csr_ea[3 * i], ea1 = csr_ea[3 * i + 1], ea2 = csr_ea[3 * i + 2];
        float m = x[s * IN_DIM + c] + ea0 * w0 + ea1 * w1 + ea2 * w2 + bb;
        acc += fmaxf(m, 0.f);
    }
    float epsv = 1.0f + epsp[0];
    Z0[n * IN_DIM + c] = epsv * x[n * IN_DIM + c] + acc;
}

// ---------------- layer 1..4 aggregation (128 ch), fp16 gather table ----------
__global__ void k_agg128(const float* __restrict__ h, const __half* __restrict__ hh,
                         const int* __restrict__ rowstart,
                         const int* __restrict__ csr_src, const float* __restrict__ csr_ea,
                         const float* __restrict__ ew, const float* __restrict__ eb,
                         const float* __restrict__ epsp, int layer, float* __restrict__ Z) {
    int wave = (blockIdx.x * blockDim.x + threadIdx.x) >> 6;
    int lane = threadIdx.x & 63;
    if (wave >= N_NODES) return;
    int n = wave;
    int c = lane * 2;
    float2 w0 = *(const float2*)(ew + 0 * HID + c);
    float2 w1 = *(const float2*)(ew + 1 * HID + c);
    float2 w2 = *(const float2*)(ew + 2 * HID + c);
    float2 bb = *(const float2*)(eb + c);
    float accx = 0.f, accy = 0.f;
    int i0 = rowstart[n], i1 = rowstart[n + 1];
#pragma unroll 2
    for (int i = i0; i < i1; ++i) {
        int s = csr_src[i];
        float ea0 = csr_ea[3 * i], ea1 = csr_ea[3 * i + 1], ea2 = csr_ea[3 * i + 2];
        __half2 hv = *(const __half2*)(hh + (size_t)s * HID + c);
        float2 hf = __half22float2(hv);
        float mx = hf.x + ea0 * w0.x + ea1 * w1.x + ea2 * w2.x + bb.x;
        float my = hf.y + ea0 * w0.y + ea1 * w1.y + ea2 * w2.y + bb.y;
        accx += fmaxf(mx, 0.f);
        accy += fmaxf(my, 0.f);
    }
    float epsv = 1.0f + epsp[layer];
    float2 hn = *(const float2*)(h + (size_t)n * HID + c);
    float2 z;
    z.x = epsv * hn.x + accx;
    z.y = epsv * hn.y + accy;
    *(float2*)(Z + (size_t)n * HID + c) = z;
}

// ---------------- MFMA node MLP: Hpre = relu(Z@W1+b1)@W2+b2, + BN stats ----------------
template <int K1>
__global__ __launch_bounds__(256, 4) void k_mlp(const float* Zin,
        const unsigned short* __restrict__ W1hi, const unsigned short* __restrict__ W1lo,
        const unsigned short* __restrict__ W2hi, const unsigned short* __restrict__ W2lo,
        const float* __restrict__ B1, const float* __restrict__ B2,
        float* Hpre, float* __restrict__ stats) {
    constexpr int KC1 = (K1 == 128) ? 4 : 1;
    __shared__ __align__(16) unsigned short ahi[4 * 4 * 64 * 8];   // 16 KB
    __shared__ __align__(16) unsigned short alo[4 * 4 * 64 * 8];   // 16 KB
    __shared__ float red[1024];                                    // 4 KB
    const int tid = threadIdx.x;
    const int w = tid >> 6;          // wave 0..3
    const int l = tid & 63;          // lane
    const int row0 = blockIdx.x * 64;

    if (K1 == 128) {
#pragma unroll
        for (int it = 0; it < 4; ++it) {
            int s = tid + it * 256;                 // s = ((wr*4+kc)*64+lane)
            int lane = s & 63, kc = (s >> 6) & 3, wr = s >> 8;
            int r = row0 + wr * 16 + (lane & 15);
            int k0 = kc * 32 + 8 * (lane >> 4);
            float v[8];
            if (r < N_NODES) {
                *(float4*)(v) = *(const float4*)(Zin + (size_t)r * 128 + k0);
                *(float4*)(v + 4) = *(const float4*)(Zin + (size_t)r * 128 + k0 + 4);
            } else {
#pragma unroll
                for (int j = 0; j < 8; ++j) v[j] = 0.f;
            }
            unsigned short h[8], q[8];
#pragma unroll
            for (int j = 0; j < 8; ++j) split_bf16(v[j], h[j], q[j]);
            *(uint4*)(ahi + (size_t)s * 8) = pack8(h);
            *(uint4*)(alo + (size_t)s * 8) = pack8(q);
        }
    } else {
        int lane = tid & 63, wr = tid >> 6;
        int r = row0 + wr * 16 + (lane & 15);
        int k0 = 8 * (lane >> 4);
        float v[8];
#pragma unroll
        for (int j = 0; j < 8; ++j) {
            int k = k0 + j;
            v[j] = (r < N_NODES && k < IN_DIM) ? Zin[(size_t)r * IN_DIM + k] : 0.f;
        }
        unsigned short h[8], q[8];
#pragma unroll
        for (int j = 0; j < 8; ++j) split_bf16(v[j], h[j], q[j]);
        size_t s = (size_t)(wr * 4 + 0) * 64 + lane;
        *(uint4*)(ahi + s * 8) = pack8(h);
        *(uint4*)(alo + s * 8) = pack8(q);
    }
    __syncthreads();

    const int cb0 = 2 * w, cb1 = cb0 + 1;
    const f32x4 zf = {0.f, 0.f, 0.f, 0.f};

    // ---- stage 1: T = relu(Z @ W1 + b1) ----
    f32x4 acc[4][2];
#pragma unroll
    for (int wr = 0; wr < 4; ++wr) { acc[wr][0] = zf; acc[wr][1] = zf; }

#pragma unroll
    for (int kc = 0; kc < KC1; ++kc) {
        bf16x8 bh0 = as_bf16x8(*(const uint4*)(W1hi + ((size_t)(kc * 8 + cb0) * 64 + l) * 8));
        bf16x8 bl0 = as_bf16x8(*(const uint4*)(W1lo + ((size_t)(kc * 8 + cb0) * 64 + l) * 8));
        bf16x8 bh1 = as_bf16x8(*(const uint4*)(W1hi + ((size_t)(kc * 8 + cb1) * 64 + l) * 8));
        bf16x8 bl1 = as_bf16x8(*(const uint4*)(W1lo + ((size_t)(kc * 8 + cb1) * 64 + l) * 8));
#pragma unroll
        for (int wr = 0; wr < 4; ++wr) {
            bf16x8 a_h = as_bf16x8(*(const uint4*)(ahi + ((size_t)(wr * 4 + kc) * 64 + l) * 8));
            bf16x8 a_l = as_bf16x8(*(const uint4*)(alo + ((size_t)(wr * 4 + kc) * 64 + l) * 8));
            acc[wr][0] = __builtin_amdgcn_mfma_f32_16x16x32_bf16(a_h, bh0, acc[wr][0], 0, 0, 0);
            acc[wr][1] = __builtin_amdgcn_mfma_f32_16x16x32_bf16(a_h, bh1, acc[wr][1], 0, 0, 0);
            acc[wr][0] = __builtin_amdgcn_mfma_f32_16x16x32_bf16(a_l, bh0, acc[wr][0], 0, 0, 0);
            acc[wr][1] = __builtin_amdgcn_mfma_f32_16x16x32_bf16(a_l, bh1, acc[wr][1], 0, 0, 0);
            acc[wr][0] = __builtin_amdgcn_mfma_f32_16x16x32_bf16(a_h, bl0, acc[wr][0], 0, 0, 0);
            acc[wr][1] = __builtin_amdgcn_mfma_f32_16x16x32_bf16(a_h, bl1, acc[wr][1], 0, 0, 0);
        }
    }
    __syncthreads();   // all stage-1 A reads done; reuse ahi/alo for T

    // ---- bias+relu, repack T into A-fragment layout ----
    {
        float b1c0 = B1[cb0 * 16 + (l & 15)];
        float b1c1 = B1[cb1 * 16 + (l & 15)];
        int j2 = l & 7;
        int hi16 = (l & 15) >> 3;
        int l2r = (l >> 4) * 4;
#pragma unroll
        for (int wr = 0; wr < 4; ++wr) {
#pragma unroll
            for (int cbl = 0; cbl < 2; ++cbl) {
                float bv = cbl ? b1c1 : b1c0;
                f32x4 v = acc[wr][cbl];
#pragma unroll
                for (int r = 0; r < 4; ++r) {
                    float t = fmaxf(v[r] + bv, 0.f);
                    unsigned short hh, qq;
                    split_bf16(t, hh, qq);
                    int l2 = l2r + r + 16 * (2 * cbl + hi16);
                    int off = ((wr * 4 + w) * 64 + l2) * 8 + j2;
                    ahi[off] = hh;
                    alo[off] = qq;
                }
            }
        }
    }
    __syncthreads();

    // ---- stage 2: out = T @ W2 + b2 ----
    f32x4 acc2[4][2];
#pragma unroll
    for (int wr = 0; wr < 4; ++wr) { acc2[wr][0] = zf; acc2[wr][1] = zf; }

#pragma unroll
    for (int kc = 0; kc < 4; ++kc) {
        bf16x8 bh0 = as_bf16x8(*(const uint4*)(W2hi + ((size_t)(kc * 8 + cb0) * 64 + l) * 8));
        bf16x8 bl0 = as_bf16x8(*(const uint4*)(W2lo + ((size_t)(kc * 8 + cb0) * 64 + l) * 8));
        bf16x8 bh1 = as_bf16x8(*(const uint4*)(W2hi + ((size_t)(kc * 8 + cb1) * 64 + l) * 8));
        bf16x8 bl1 = as_bf16x8(*(const uint4*)(W2lo + ((size_t)(kc * 8 + cb1) * 64 + l) * 8));
#pragma unroll
        for (int wr = 0; wr < 4; ++wr) {
            bf16x8 a_h = as_bf16x8(*(const uint4*)(ahi + ((size_t)(wr * 4 + kc) * 64 + l) * 8));
            bf16x8 a_l = as_bf16x8(*(const uint4*)(alo + ((size_t)(wr * 4 + kc) * 64 + l) * 8));
            acc2[wr][0] = __builtin_amdgcn_mfma_f32_16x16x32_bf16(a_h, bh0, acc2[wr][0], 0, 0, 0);
            acc2[wr][1] = __builtin_amdgcn_mfma_f32_16x16x32_bf16(a_h, bh1, acc2[wr][1], 0, 0, 0);
            acc2[wr][0] = __builtin_amdgcn_mfma_f32_16x16x32_bf16(a_l, bh0, acc2[wr][0], 0, 0, 0);
            acc2[wr][1] = __builtin_amdgcn_mfma_f32_16x16x32_bf16(a_l, bh1, acc2[wr][1], 0, 0, 0);
            acc2[wr][0] = __builtin_amdgcn_mfma_f32_16x16x32_bf16(a_h, bl0, acc2[wr][0], 0, 0, 0);
            acc2[wr][1] = __builtin_amdgcn_mfma_f32_16x16x32_bf16(a_h, bl1, acc2[wr][1], 0, 0, 0);
        }
    }

    // ---- epilogue: bias, store Hpre, BN partial stats ----
    {
        float b2c0 = B2[cb0 * 16 + (l & 15)];
        float b2c1 = B2[cb1 * 16 + (l & 15)];
        float s0 = 0.f, q0 = 0.f, s1 = 0.f, q1 = 0.f;
#pragma unroll
        for (int wr = 0; wr < 4; ++wr) {
#pragma unroll
            for (int r = 0; r < 4; ++r) {
                int grow = row0 + wr * 16 + (l >> 4) * 4 + r;
                if (grow < N_NODES) {
                    float o0 = acc2[wr][0][r] + b2c0;
                    float o1 = acc2[wr][1][r] + b2c1;
                    Hpre[(size_t)grow * 128 + cb0 * 16 + (l & 15)] = o0;
                    Hpre[(size_t)grow * 128 + cb1 * 16 + (l & 15)] = o1;
                    s0 += o0; q0 += o0 * o0;
                    s1 += o1; q1 += o1 * o1;
                }
            }
        }
        red[(w * 2 + 0) * 64 + l] = s0;
        red[(w * 2 + 1) * 64 + l] = s1;
        red[512 + (w * 2 + 0) * 64 + l] = q0;
        red[512 + (w * 2 + 1) * 64 + l] = q1;
    }
    __syncthreads();
    if (tid < 128) {
        int b = ((tid >> 5) * 2 + ((tid >> 4) & 1)) * 64 + (tid & 15);
        float ss = red[b] + red[b + 16] + red[b + 32] + red[b + 48];
        float qq = red[512 + b] + red[512 + b + 16] + red[512 + b + 32] + red[512 + b + 48];
        atomicAdd(&stats[tid], ss);
        atomicAdd(&stats[128 + tid], qq);
    }
}

// ---------------- BN normalize + relu (+residual), writes h (+fp16 shadow) -----------
__global__ void k_bn(const float* __restrict__ Hpre, const float* __restrict__ stats,
                     const float* __restrict__ gamma, const float* __restrict__ beta,
                     float* __restrict__ h, __half* __restrict__ hh, int residual) {
    int idx = blockIdx.x * 256 + threadIdx.x;   // float4 index into [N,128]
    const float invN = 1.f / (float)N_NODES;
    int c4 = idx & 31;
    float4 v = ((const float4*)Hpre)[idx];
    float4 s0 = ((const float4*)stats)[c4];
    float4 s1 = ((const float4*)(stats + 128))[c4];
    float4 g = ((const float4*)gamma)[c4];
    float4 bt = ((const float4*)beta)[c4];
    float4 r;
    {
        float mu = s0.x * invN, var = s1.x * invN - mu * mu;
        r.x = fmaxf((v.x - mu) * rsqrtf(var + BN_EPS) * g.x + bt.x, 0.f);
    }
    {
        float mu = s0.y * invN, var = s1.y * invN - mu * mu;
        r.y = fmaxf((v.y - mu) * rsqrtf(var + BN_EPS) * g.y + bt.y, 0.f);
    }
    {
        float mu = s0.z * invN, var = s1.z * invN - mu * mu;
        r.z = fmaxf((v.z - mu) * rsqrtf(var + BN_EPS) * g.z + bt.z, 0.f);
    }
    {
        float mu = s0.w * invN, var = s1.w * invN - mu * mu;
        r.w = fmaxf((v.w - mu) * rsqrtf(var + BN_EPS) * g.w + bt.w, 0.f);
    }
    if (residual) {
        float4 hv = ((const float4*)h)[idx];
        r.x += hv.x; r.y += hv.y; r.z += hv.z; r.w += hv.w;
    }
    ((float4*)h)[idx] = r;
    if (hh) {
        __half2 p0 = __floats2half2_rn(r.x, r.y);
        __half2 p1 = __floats2half2_rn(r.z, r.w);
        uint2 pk;
        pk.x = __builtin_bit_cast(unsigned int, p0);
        pk.y = __builtin_bit_cast(unsigned int, p1);
        *(uint2*)(hh + (size_t)idx * 4) = pk;
    }
}

// ---------------- graph boundaries (batch is sorted) ----------------
__global__ void k_bounds(const int* __restrict__ batch, int* __restrict__ gstart,
                         int* __restrict__ gend) {
    int r = blockIdx.x * 256 + threadIdx.x;
    if (r >= N_NODES) return;
    int b = batch[r];
    if (r == 0 || batch[r - 1] != b) gstart[b] = r;
    if (r == N_NODES - 1 || batch[r + 1] != b) gend[b] = r + 1;
}

// ---------------- mean pool per graph (wave per graph) ----------------
__global__ void k_pool(const float* __restrict__ h, const int* __restrict__ gstart,
                       const int* __restrict__ gend, float* __restrict__ pooled) {
    int wave = (blockIdx.x * blockDim.x + threadIdx.x) >> 6;
    int lane = threadIdx.x & 63;
    if (wave >= N_GRAPHS) return;
    int g = wave;
    int c = lane * 2;
    int a = gstart[g], b = gend[g];
    float ax = 0.f, ay = 0.f;
    for (int r = a; r < b; ++r) {
        float2 v = *(const float2*)(h + (size_t)r * HID + c);
        ax += v.x;
        ay += v.y;
    }
    float d = fmaxf((float)(b - a), 1.f);
    float2 o;
    o.x = ax / d;
    o.y = ay / d;
    *(float2*)(pooled + (size_t)g * HID + c) = o;
}

// ---------------- head MLP ----------------
__global__ void k_head(const float* __restrict__ pooled, const float* __restrict__ hw1,
                       const float* __restrict__ hb1, const float* __restrict__ hw2,
                       const float* __restrict__ hb2, const float* __restrict__ hw3,
                       const float* __restrict__ hb3, float* __restrict__ out) {
    __shared__ float ps[2][128];
    __shared__ float t1s[2][128];
    __shared__ float red[256];
    int tid = threadIdx.x;
    int rr = tid >> 7, c = tid & 127;
    int row = blockIdx.x * 2 + rr;
    ps[rr][c] = pooled[(size_t)row * 128 + c];
    __syncthreads();
    float a = hb1[c];
    for (int k = 0; k < 128; ++k) a = fmaf(ps[rr][k], hw1[k * 128 + c], a);
    t1s[rr][c] = fmaxf(a, 0.f);
    __syncthreads();
    float b = hb2[c];
    for (int k = 0; k < 128; ++k) b = fmaf(t1s[rr][k], hw2[k * 128 + c], b);
    b = fmaxf(b, 0.f);
    red[tid] = b * hw3[c];
    for (int s = 64; s > 0; s >>= 1) {
        __syncthreads();
        if (c < s) red[tid] += red[tid + s];
    }
    __syncthreads();
    if (c == 0) out[row] = red[tid] + hb3[0];
}

// ---------------- launch ----------------
extern "C" void kernel_launch(void* const* d_in, const int* in_sizes, int n_in,
                              void* d_out, int out_size, void* d_ws, size_t ws_size,
                              hipStream_t stream) {
    const float* x = (const float*)d_in[0];
    const float* edge_attr = (const float*)d_in[1];
    const float* e_w0 = (const float*)d_in[2];
    const float* e_b0 = (const float*)d_in[3];
    const float* w1_0 = (const float*)d_in[4];
    const float* b1_0 = (const float*)d_in[5];
    const float* w2_0 = (const float*)d_in[6];
    const float* b2_0 = (const float*)d_in[7];
    const float* gamma0 = (const float*)d_in[8];
    const float* beta0 = (const float*)d_in[9];
    const float* eps0 = (const float*)d_in[10];
    const float* e_w = (const float*)d_in[11];
    const float* e_b = (const float*)d_in[12];
    const float* w1 = (const float*)d_in[13];
    const float* b1 = (const float*)d_in[14];
    const float* w2 = (const float*)d_in[15];
    const float* b2 = (const float*)d_in[16];
    const float* gamma = (const float*)d_in[17];
    const float* beta = (const float*)d_in[18];
    const float* eps_r = (const float*)d_in[19];
    const float* hw1 = (const float*)d_in[20];
    const float* hb1 = (const float*)d_in[21];
    const float* hw2 = (const float*)d_in[22];
    const float* hb2 = (const float*)d_in[23];
    const float* hw3 = (const float*)d_in[24];
    const float* hb3 = (const float*)d_in[25];
    const int* edge_index = (const int*)d_in[26];
    const int* batch = (const int*)d_in[27];
    float* out = (float*)d_out;

    // workspace layout
    float* wsf = (float*)d_ws;
    size_t off = 0;
    float* A = wsf + off;      off += (size_t)N_NODES * HID;   // h
    float* ZB = wsf + off;     off += (size_t)N_NODES * HID;   // Z / hpre (aliased per-tile)
    float* Z0 = wsf + off;     off += (size_t)N_NODES * IN_DIM;
    float* pooled = wsf + off; off += (size_t)N_GRAPHS * HID;
    float* stats = wsf + off;  off += 5 * 2 * HID;
    float* csr_ea = wsf + off; off += (size_t)3 * N_EDGES;
    __half* hhalf = (__half*)(wsf + off); off += (size_t)N_NODES * HID / 2;  // fp16 shadow
    int* ib = (int*)(wsf + off);
    size_t io = 0;
    int* deg = ib + io;      io += N_NODES;
    int* rowstart = ib + io; io += N_NODES + 4;
    int* cur = ib + io;      io += N_NODES;
    int* csr_src = ib + io;  io += N_EDGES;
    int* gstart = ib + io;   io += N_GRAPHS;
    int* gend = ib + io;     io += N_GRAPHS;
    int* bsum = ib + io;     io += 512;
    int* boff = ib + io;     io += 512;
    unsigned short* Whi = (unsigned short*)(ib + io);          // 10 slots * 16384 ushorts
    unsigned short* Wlo = Whi + 10 * WSLOT;

    const int EB = (N_EDGES + 255) / 256;        // 2344
    const int NB = (N_NODES + 255) / 256;        // 391
    const int MLPB = (N_NODES + 63) / 64;        // 1563

    // zero control buffers + pack weights (ws is poisoned before every call)
    k_zero<<<NB, 256, 0, stream>>>(deg, gstart, gend, stats);
    k_pack<<<320, 64, 0, stream>>>(w1_0, w2_0, w1, w2, Whi, Wlo);

    // CSR build
    k_deg<<<EB, 256, 0, stream>>>(edge_index, deg);
    k_scan_a<<<NBLK, SCAN_BS, 0, stream>>>(deg, rowstart, bsum);
    k_scan_b<<<1, 512, 0, stream>>>(bsum, boff);
    k_scan_c<<<NB, 256, 0, stream>>>(rowstart, boff, cur);
    k_fill<<<EB, 256, 0, stream>>>(edge_index, edge_attr, cur, csr_src, csr_ea);

    // layer 0
    k_agg0<<<(N_NODES * 64) / 256, 256, 0, stream>>>(x, rowstart, csr_src, csr_ea, e_w0,
                                                     e_b0, eps0, Z0);
    k_mlp<IN_DIM><<<MLPB, 256, 0, stream>>>(Z0, Whi + 0 * WSLOT, Wlo + 0 * WSLOT,
                                            Whi + 1 * WSLOT, Wlo + 1 * WSLOT,
                                            b1_0, b2_0, ZB, stats);
    k_bn<<<(N_NODES * HID / 4) / 256, 256, 0, stream>>>(ZB, stats, gamma0, beta0, A,
                                                        hhalf, 0);

    // layers 1..4
    for (int i = 0; i < NREST; ++i) {
        k_agg128<<<(N_NODES * 64) / 256, 256, 0, stream>>>(
            A, hhalf, rowstart, csr_src, csr_ea, e_w + (size_t)i * 3 * HID,
            e_b + (size_t)i * HID, eps_r, i, ZB);
        k_mlp<HID><<<MLPB, 256, 0, stream>>>(ZB, Whi + (size_t)(2 + i) * WSLOT,
                                             Wlo + (size_t)(2 + i) * WSLOT,
                                             Whi + (size_t)(6 + i) * WSLOT,
                                             Wlo + (size_t)(6 + i) * WSLOT,
                                             b1 + (size_t)i * HID, b2 + (size_t)i * HID,
                                             ZB, stats + (size_t)(i + 1) * 2 * HID);
        k_bn<<<(N_NODES * HID / 4) / 256, 256, 0, stream>>>(
            ZB, stats + (size_t)(i + 1) * 2 * HID, gamma + (size_t)i * HID,
            beta + (size_t)i * HID, A, (i < NREST - 1) ? hhalf : (__half*)nullptr, 1);
    }

    // pooling + head
    k_bounds<<<NB, 256, 0, stream>>>(batch, gstart, gend);
    k_pool<<<(N_GRAPHS * 64) / 256, 256, 0, stream>>>(A, gstart, gend, pooled);
    k_head<<<N_GRAPHS / 2, 256, 0, stream>>>(pooled, hw1, hb1, hw2, hb2, hw3, hb3, out);
}

// Round 5
// 901.537 us; speedup vs baseline: 1.5280x; 1.0464x over previous
//
#include <hip/hip_runtime.h>
#include <hip/hip_fp16.h>

#define N_NODES 100000
#define N_EDGES 600000
#define N_GRAPHS 5000
#define IN_DIM 11
#define HID 128
#define NREST 4
#define BN_EPS 1e-5f
#define SCAN_BS 256
#define NBLK ((N_NODES + SCAN_BS - 1) / SCAN_BS)   // 391
#define WSLOT 16384                                // ushorts per packed weight slot

typedef __bf16 bf16x8 __attribute__((ext_vector_type(8)));
typedef float f32x4 __attribute__((ext_vector_type(4)));

__device__ inline bf16x8 as_bf16x8(uint4 u) { return __builtin_bit_cast(bf16x8, u); }

// fp32 -> (hi, lo) truncated bf16 pair: x ~= hi + lo with |err| <= 2^-16 |x|
__device__ inline void split_bf16(float x, unsigned short& hi, unsigned short& lo) {
    unsigned int b = __float_as_uint(x);
    hi = (unsigned short)(b >> 16);
    float rem = x - __uint_as_float(b & 0xFFFF0000u);
    lo = (unsigned short)(__float_as_uint(rem) >> 16);
}

__device__ inline uint4 pack8(const unsigned short* h) {
    uint4 u;
    u.x = (unsigned)h[0] | ((unsigned)h[1] << 16);
    u.y = (unsigned)h[2] | ((unsigned)h[3] << 16);
    u.z = (unsigned)h[4] | ((unsigned)h[5] << 16);
    u.w = (unsigned)h[6] | ((unsigned)h[7] << 16);
    return u;
}

// ---------------- utility: zero the small control buffers ----------------
__global__ void k_zero(int* deg, int* gstart, int* gend, float* stats) {
    int i = blockIdx.x * 256 + threadIdx.x;
    if (i < N_NODES) deg[i] = 0;
    if (i < N_GRAPHS) { gstart[i] = 0; gend[i] = 0; }
    if (i < 5 * 2 * HID) stats[i] = 0.f;
}

// ---------------- CSR build (by dst) ----------------
__global__ void k_deg(const int* __restrict__ ei, int* __restrict__ deg) {
    int e = blockIdx.x * 256 + threadIdx.x;
    if (e < N_EDGES) atomicAdd(&deg[ei[N_EDGES + e]], 1);
}

__global__ void k_scan_a(const int* __restrict__ deg, int* __restrict__ rowstart,
                         int* __restrict__ bsum) {
    __shared__ int sh[SCAN_BS];
    int t = threadIdx.x, i = blockIdx.x * SCAN_BS + t;
    int v = (i < N_NODES) ? deg[i] : 0;
    sh[t] = v;
    __syncthreads();
    for (int off = 1; off < SCAN_BS; off <<= 1) {
        int add = (t >= off) ? sh[t - off] : 0;
        __syncthreads();
        sh[t] += add;
        __syncthreads();
    }
    if (i < N_NODES) rowstart[i] = sh[t] - v;
    if (t == SCAN_BS - 1) bsum[blockIdx.x] = sh[t];
}

__global__ void k_scan_b(const int* __restrict__ bsum, int* __restrict__ boff) {
    __shared__ int sh[512];
    int t = threadIdx.x;
    int v = (t < NBLK) ? bsum[t] : 0;
    sh[t] = v;
    __syncthreads();
    for (int off = 1; off < 512; off <<= 1) {
        int add = (t >= off) ? sh[t - off] : 0;
        __syncthreads();
        sh[t] += add;
        __syncthreads();
    }
    if (t < NBLK) boff[t] = sh[t] - v;
}

__global__ void k_scan_c(int* __restrict__ rowstart, const int* __restrict__ boff,
                         int* __restrict__ cur) {
    int i = blockIdx.x * 256 + threadIdx.x;
    if (i < N_NODES) {
        int v = rowstart[i] + boff[i / SCAN_BS];
        rowstart[i] = v;
        cur[i] = v;
    }
    if (i == 0) rowstart[N_NODES] = N_EDGES;
}

__global__ void k_fill(const int* __restrict__ ei, const float* __restrict__ ea,
                       int* __restrict__ cur, int* __restrict__ csr_src,
                       float* __restrict__ csr_ea) {
    int e = blockIdx.x * 256 + threadIdx.x;
    if (e < N_EDGES) {
        int d = ei[N_EDGES + e];
        int p = atomicAdd(&cur[d], 1);
        csr_src[p] = ei[e];
        csr_ea[3 * p + 0] = ea[3 * e + 0];
        csr_ea[3 * p + 1] = ea[3 * e + 1];
        csr_ea[3 * p + 2] = ea[3 * e + 2];
    }
}

// ---------------- weight pre-pack into MFMA B-fragment layout (hi/lo bf16) -------------
__global__ void k_pack(const float* __restrict__ w1_0, const float* __restrict__ w2_0,
                       const float* __restrict__ w1, const float* __restrict__ w2,
                       unsigned short* __restrict__ Whi, unsigned short* __restrict__ Wlo) {
    int bid = blockIdx.x;              // slot*32 + kc*8 + cb
    int slot = bid >> 5;
    int kc = (bid >> 3) & 3, cb = bid & 7;
    int lane = threadIdx.x;            // 64 threads
    const float* src;
    int K;
    if (slot == 0) { src = w1_0; K = IN_DIM; }
    else if (slot == 1) { src = w2_0; K = HID; }
    else if (slot < 6) { src = w1 + (size_t)(slot - 2) * HID * HID; K = HID; }
    else { src = w2 + (size_t)(slot - 6) * HID * HID; K = HID; }
    int col = cb * 16 + (lane & 15);
    int kbase = kc * 32 + 8 * (lane >> 4);
    unsigned short hi[8], lo[8];
#pragma unroll
    for (int j = 0; j < 8; ++j) {
        int k = kbase + j;
        float v = (k < K) ? src[(size_t)k * HID + col] : 0.f;
        split_bf16(v, hi[j], lo[j]);
    }
    size_t base = ((size_t)bid * 64 + lane) * 8;
    *(uint4*)(Whi + base) = pack8(hi);
    *(uint4*)(Wlo + base) = pack8(lo);
}

// ---------------- layer-0 aggregation (11 ch), 4 edge-slots/wave ----------
__global__ void k_agg0(const float* __restrict__ x, const int* __restrict__ rowstart,
                       const int* __restrict__ csr_src, const float* __restrict__ csr_ea,
                       const float* __restrict__ ew, const float* __restrict__ eb,
                       const float* __restrict__ epsp, float* __restrict__ Z0) {
    int wave = (blockIdx.x * blockDim.x + threadIdx.x) >> 6;
    int lane = threadIdx.x & 63;
    if (wave >= N_NODES) return;
    int n = wave;
    int slot = lane >> 4;            // 0..3: which edge this lane-group works on
    int c = lane & 15;               // channel (active if < 11)
    int cc = (c < IN_DIM) ? c : 0;   // clamp for safe loads; result unused if inactive
    float w0 = ew[0 * IN_DIM + cc], w1 = ew[1 * IN_DIM + cc], w2 = ew[2 * IN_DIM + cc];
    float bb = eb[cc];
    float acc = 0.f;
    int i0 = rowstart[n], i1 = rowstart[n + 1];
    for (int i = i0 + slot; i < i1; i += 4) {
        int s = csr_src[i];
        float ea0 = csr_ea[3 * i], ea1 = csr_ea[3 * i + 1], ea2 = csr_ea[3 * i + 2];
        float m = x[s * IN_DIM + cc] + ea0 * w0 + ea1 * w1 + ea2 * w2 + bb;
        acc += fmaxf(m, 0.f);
    }
    // reduce over the 4 slots (xor 16/32 only mix lanes with identical c)
    acc += __shfl_xor(acc, 16, 64);
    acc += __shfl_xor(acc, 32, 64);
    if (lane < IN_DIM) {
        float epsv = 1.0f + epsp[0];
        Z0[n * IN_DIM + lane] = epsv * x[n * IN_DIM + lane] + acc;
    }
}

// ---------------- layer 1..4 aggregation (128 ch), fp16 table, 4 edge-slots/wave ------
__global__ void k_agg128(const float* __restrict__ h, const __half* __restrict__ hh,
                         const int* __restrict__ rowstart,
                         const int* __restrict__ csr_src, const float* __restrict__ csr_ea,
                         const float* __restrict__ ew, const float* __restrict__ eb,
                         const float* __restrict__ epsp, int layer, float* __restrict__ Z) {
    int wave = (blockIdx.x * blockDim.x + threadIdx.x) >> 6;
    int lane = threadIdx.x & 63;
    if (wave >= N_NODES) return;
    int n = wave;
    int slot = lane >> 4;            // 0..3: edge slot
    int c = (lane & 15) * 8;         // 8 channels per lane
    float4 w0a = *(const float4*)(ew + 0 * HID + c), w0b = *(const float4*)(ew + 0 * HID + c + 4);
    float4 w1a = *(const float4*)(ew + 1 * HID + c), w1b = *(const float4*)(ew + 1 * HID + c + 4);
    float4 w2a = *(const float4*)(ew + 2 * HID + c), w2b = *(const float4*)(ew + 2 * HID + c + 4);
    float4 bba = *(const float4*)(eb + c),           bbb = *(const float4*)(eb + c + 4);
    float a0 = 0.f, a1 = 0.f, a2 = 0.f, a3 = 0.f, a4 = 0.f, a5 = 0.f, a6 = 0.f, a7 = 0.f;
    int i0 = rowstart[n], i1 = rowstart[n + 1];
    for (int i = i0 + slot; i < i1; i += 4) {
        int s = csr_src[i];
        float ea0 = csr_ea[3 * i], ea1 = csr_ea[3 * i + 1], ea2 = csr_ea[3 * i + 2];
        uint4 hv = *(const uint4*)(hh + (size_t)s * HID + c);    // 8 fp16 = 16 B
        float2 f0 = __half22float2(__builtin_bit_cast(__half2, hv.x));
        float2 f1 = __half22float2(__builtin_bit_cast(__half2, hv.y));
        float2 f2 = __half22float2(__builtin_bit_cast(__half2, hv.z));
        float2 f3 = __half22float2(__builtin_bit_cast(__half2, hv.w));
        a0 += fmaxf(f0.x + ea0 * w0a.x + ea1 * w1a.x + ea2 * w2a.x + bba.x, 0.f);
        a1 += fmaxf(f0.y + ea0 * w0a.y + ea1 * w1a.y + ea2 * w2a.y + bba.y, 0.f);
        a2 += fmaxf(f1.x + ea0 * w0a.z + ea1 * w1a.z + ea2 * w2a.z + bba.z, 0.f);
        a3 += fmaxf(f1.y + ea0 * w0a.w + ea1 * w1a.w + ea2 * w2a.w + bba.w, 0.f);
        a4 += fmaxf(f2.x + ea0 * w0b.x + ea1 * w1b.x + ea2 * w2b.x + bbb.x, 0.f);
        a5 += fmaxf(f2.y + ea0 * w0b.y + ea1 * w1b.y + ea2 * w2b.y + bbb.y, 0.f);
        a6 += fmaxf(f3.x + ea0 * w0b.z + ea1 * w1b.z + ea2 * w2b.z + bbb.z, 0.f);
        a7 += fmaxf(f3.y + ea0 * w0b.w + ea1 * w1b.w + ea2 * w2b.w + bbb.w, 0.f);
    }
    // reduce the 4 slots; xor 16/32 only mix lanes with identical channel set
#pragma unroll
    for (int m = 16; m <= 32; m <<= 1) {
        a0 += __shfl_xor(a0, m, 64); a1 += __shfl_xor(a1, m, 64);
        a2 += __shfl_xor(a2, m, 64); a3 += __shfl_xor(a3, m, 64);
        a4 += __shfl_xor(a4, m, 64); a5 += __shfl_xor(a5, m, 64);
        a6 += __shfl_xor(a6, m, 64); a7 += __shfl_xor(a7, m, 64);
    }
    if (slot == 0) {
        float epsv = 1.0f + epsp[layer];
        float4 hna = *(const float4*)(h + (size_t)n * HID + c);
        float4 hnb = *(const float4*)(h + (size_t)n * HID + c + 4);
        float4 za, zb;
        za.x = epsv * hna.x + a0; za.y = epsv * hna.y + a1;
        za.z = epsv * hna.z + a2; za.w = epsv * hna.w + a3;
        zb.x = epsv * hnb.x + a4; zb.y = epsv * hnb.y + a5;
        zb.z = epsv * hnb.z + a6; zb.w = epsv * hnb.w + a7;
        *(float4*)(Z + (size_t)n * HID + c) = za;
        *(float4*)(Z + (size_t)n * HID + c + 4) = zb;
    }
}

// ---------------- MFMA node MLP: Hpre = relu(Z@W1+b1)@W2+b2, + BN stats ----------------
template <int K1>
__global__ __launch_bounds__(256, 4) void k_mlp(const float* Zin,
        const unsigned short* __restrict__ W1hi, const unsigned short* __restrict__ W1lo,
        const unsigned short* __restrict__ W2hi, const unsigned short* __restrict__ W2lo,
        const float* __restrict__ B1, const float* __restrict__ B2,
        float* Hpre, float* __restrict__ stats) {
    constexpr int KC1 = (K1 == 128) ? 4 : 1;
    __shared__ __align__(16) unsigned short ahi[4 * 4 * 64 * 8];   // 16 KB
    __shared__ __align__(16) unsigned short alo[4 * 4 * 64 * 8];   // 16 KB
    __shared__ float red[1024];                                    // 4 KB
    const int tid = threadIdx.x;
    const int w = tid >> 6;          // wave 0..3
    const int l = tid & 63;          // lane
    const int row0 = blockIdx.x * 64;

    if (K1 == 128) {
#pragma unroll
        for (int it = 0; it < 4; ++it) {
            int s = tid + it * 256;                 // s = ((wr*4+kc)*64+lane)
            int lane = s & 63, kc = (s >> 6) & 3, wr = s >> 8;
            int r = row0 + wr * 16 + (lane & 15);
            int k0 = kc * 32 + 8 * (lane >> 4);
            float v[8];
            if (r < N_NODES) {
                *(float4*)(v) = *(const float4*)(Zin + (size_t)r * 128 + k0);
                *(float4*)(v + 4) = *(const float4*)(Zin + (size_t)r * 128 + k0 + 4);
            } else {
#pragma unroll
                for (int j = 0; j < 8; ++j) v[j] = 0.f;
            }
            unsigned short h[8], q[8];
#pragma unroll
            for (int j = 0; j < 8; ++j) split_bf16(v[j], h[j], q[j]);
            *(uint4*)(ahi + (size_t)s * 8) = pack8(h);
            *(uint4*)(alo + (size_t)s * 8) = pack8(q);
        }
    } else {
        int lane = tid & 63, wr = tid >> 6;
        int r = row0 + wr * 16 + (lane & 15);
        int k0 = 8 * (lane >> 4);
        float v[8];
#pragma unroll
        for (int j = 0; j < 8; ++j) {
            int k = k0 + j;
            v[j] = (r < N_NODES && k < IN_DIM) ? Zin[(size_t)r * IN_DIM + k] : 0.f;
        }
        unsigned short h[8], q[8];
#pragma unroll
        for (int j = 0; j < 8; ++j) split_bf16(v[j], h[j], q[j]);
        size_t s = (size_t)(wr * 4 + 0) * 64 + lane;
        *(uint4*)(ahi + s * 8) = pack8(h);
        *(uint4*)(alo + s * 8) = pack8(q);
    }
    __syncthreads();

    const int cb0 = 2 * w, cb1 = cb0 + 1;
    const f32x4 zf = {0.f, 0.f, 0.f, 0.f};

    // ---- stage 1: T = relu(Z @ W1 + b1) ----
    f32x4 acc[4][2];
#pragma unroll
    for (int wr = 0; wr < 4; ++wr) { acc[wr][0] = zf; acc[wr][1] = zf; }

#pragma unroll
    for (int kc = 0; kc < KC1; ++kc) {
        bf16x8 bh0 = as_bf16x8(*(const uint4*)(W1hi + ((size_t)(kc * 8 + cb0) * 64 + l) * 8));
        bf16x8 bl0 = as_bf16x8(*(const uint4*)(W1lo + ((size_t)(kc * 8 + cb0) * 64 + l) * 8));
        bf16x8 bh1 = as_bf16x8(*(const uint4*)(W1hi + ((size_t)(kc * 8 + cb1) * 64 + l) * 8));
        bf16x8 bl1 = as_bf16x8(*(const uint4*)(W1lo + ((size_t)(kc * 8 + cb1) * 64 + l) * 8));
#pragma unroll
        for (int wr = 0; wr < 4; ++wr) {
            bf16x8 a_h = as_bf16x8(*(const uint4*)(ahi + ((size_t)(wr * 4 + kc) * 64 + l) * 8));
            bf16x8 a_l = as_bf16x8(*(const uint4*)(alo + ((size_t)(wr * 4 + kc) * 64 + l) * 8));
            acc[wr][0] = __builtin_amdgcn_mfma_f32_16x16x32_bf16(a_h, bh0, acc[wr][0], 0, 0, 0);
            acc[wr][1] = __builtin_amdgcn_mfma_f32_16x16x32_bf16(a_h, bh1, acc[wr][1], 0, 0, 0);
            acc[wr][0] = __builtin_amdgcn_mfma_f32_16x16x32_bf16(a_l, bh0, acc[wr][0], 0, 0, 0);
            acc[wr][1] = __builtin_amdgcn_mfma_f32_16x16x32_bf16(a_l, bh1, acc[wr][1], 0, 0, 0);
            acc[wr][0] = __builtin_amdgcn_mfma_f32_16x16x32_bf16(a_h, bl0, acc[wr][0], 0, 0, 0);
            acc[wr][1] = __builtin_amdgcn_mfma_f32_16x16x32_bf16(a_h, bl1, acc[wr][1], 0, 0, 0);
        }
    }
    __syncthreads();   // all stage-1 A reads done; reuse ahi/alo for T

    // ---- bias+relu, repack T into A-fragment layout ----
    {
        float b1c0 = B1[cb0 * 16 + (l & 15)];
        float b1c1 = B1[cb1 * 16 + (l & 15)];
        int j2 = l & 7;
        int hi16 = (l & 15) >> 3;
        int l2r = (l >> 4) * 4;
#pragma unroll
        for (int wr = 0; wr < 4; ++wr) {
#pragma unroll
            for (int cbl = 0; cbl < 2; ++cbl) {
                float bv = cbl ? b1c1 : b1c0;
                f32x4 v = acc[wr][cbl];
#pragma unroll
                for (int r = 0; r < 4; ++r) {
                    float t = fmaxf(v[r] + bv, 0.f);
                    unsigned short hh, qq;
                    split_bf16(t, hh, qq);
                    int l2 = l2r + r + 16 * (2 * cbl + hi16);
                    int off = ((wr * 4 + w) * 64 + l2) * 8 + j2;
                    ahi[off] = hh;
                    alo[off] = qq;
                }
            }
        }
    }
    __syncthreads();

    // ---- stage 2: out = T @ W2 + b2 ----
    f32x4 acc2[4][2];
#pragma unroll
    for (int wr = 0; wr < 4; ++wr) { acc2[wr][0] = zf; acc2[wr][1] = zf; }

#pragma unroll
    for (int kc = 0; kc < 4; ++kc) {
        bf16x8 bh0 = as_bf16x8(*(const uint4*)(W2hi + ((size_t)(kc * 8 + cb0) * 64 + l) * 8));
        bf16x8 bl0 = as_bf16x8(*(const uint4*)(W2lo + ((size_t)(kc * 8 + cb0) * 64 + l) * 8));
        bf16x8 bh1 = as_bf16x8(*(const uint4*)(W2hi + ((size_t)(kc * 8 + cb1) * 64 + l) * 8));
        bf16x8 bl1 = as_bf16x8(*(const uint4*)(W2lo + ((size_t)(kc * 8 + cb1) * 64 + l) * 8));
#pragma unroll
        for (int wr = 0; wr < 4; ++wr) {
            bf16x8 a_h = as_bf16x8(*(const uint4*)(ahi + ((size_t)(wr * 4 + kc) * 64 + l) * 8));
            bf16x8 a_l = as_bf16x8(*(const uint4*)(alo + ((size_t)(wr * 4 + kc) * 64 + l) * 8));
            acc2[wr][0] = __builtin_amdgcn_mfma_f32_16x16x32_bf16(a_h, bh0, acc2[wr][0], 0, 0, 0);
            acc2[wr][1] = __builtin_amdgcn_mfma_f32_16x16x32_bf16(a_h, bh1, acc2[wr][1], 0, 0, 0);
            acc2[wr][0] = __builtin_amdgcn_mfma_f32_16x16x32_bf16(a_l, bh0, acc2[wr][0], 0, 0, 0);
            acc2[wr][1] = __builtin_amdgcn_mfma_f32_16x16x32_bf16(a_l, bh1, acc2[wr][1], 0, 0, 0);
            acc2[wr][0] = __builtin_amdgcn_mfma_f32_16x16x32_bf16(a_h, bl0, acc2[wr][0], 0, 0, 0);
            acc2[wr][1] = __builtin_amdgcn_mfma_f32_16x16x32_bf16(a_h, bl1, acc2[wr][1], 0, 0, 0);
        }
    }

    // ---- epilogue: bias, store Hpre, BN partial stats ----
    {
        float b2c0 = B2[cb0 * 16 + (l & 15)];
        float b2c1 = B2[cb1 * 16 + (l & 15)];
        float s0 = 0.f, q0 = 0.f, s1 = 0.f, q1 = 0.f;
#pragma unroll
        for (int wr = 0; wr < 4; ++wr) {
#pragma unroll
            for (int r = 0; r < 4; ++r) {
                int grow = row0 + wr * 16 + (l >> 4) * 4 + r;
                if (grow < N_NODES) {
                    float o0 = acc2[wr][0][r] + b2c0;
                    float o1 = acc2[wr][1][r] + b2c1;
                    Hpre[(size_t)grow * 128 + cb0 * 16 + (l & 15)] = o0;
                    Hpre[(size_t)grow * 128 + cb1 * 16 + (l & 15)] = o1;
                    s0 += o0; q0 += o0 * o0;
                    s1 += o1; q1 += o1 * o1;
                }
            }
        }
        red[(w * 2 + 0) * 64 + l] = s0;
        red[(w * 2 + 1) * 64 + l] = s1;
        red[512 + (w * 2 + 0) * 64 + l] = q0;
        red[512 + (w * 2 + 1) * 64 + l] = q1;
    }
    __syncthreads();
    if (tid < 128) {
        int b = ((tid >> 5) * 2 + ((tid >> 4) & 1)) * 64 + (tid & 15);
        float ss = red[b] + red[b + 16] + red[b + 32] + red[b + 48];
        float qq = red[512 + b] + red[512 + b + 16] + red[512 + b + 32] + red[512 + b + 48];
        atomicAdd(&stats[tid], ss);
        atomicAdd(&stats[128 + tid], qq);
    }
}

// ---------------- BN normalize + relu (+residual), writes h (+fp16 shadow) -----------
__global__ void k_bn(const float* __restrict__ Hpre, const float* __restrict__ stats,
                     const float* __restrict__ gamma, const float* __restrict__ beta,
                     float* __restrict__ h, __half* __restrict__ hh, int residual) {
    int idx = blockIdx.x * 256 + threadIdx.x;   // float4 index into [N,128]
    const float invN = 1.f / (float)N_NODES;
    int c4 = idx & 31;
    float4 v = ((const float4*)Hpre)[idx];
    float4 s0 = ((const float4*)stats)[c4];
    float4 s1 = ((const float4*)(stats + 128))[c4];
    float4 g = ((const float4*)gamma)[c4];
    float4 bt = ((const float4*)beta)[c4];
    float4 r;
    {
        float mu = s0.x * invN, var = s1.x * invN - mu * mu;
        r.x = fmaxf((v.x - mu) * rsqrtf(var + BN_EPS) * g.x + bt.x, 0.f);
    }
    {
        float mu = s0.y * invN, var = s1.y * invN - mu * mu;
        r.y = fmaxf((v.y - mu) * rsqrtf(var + BN_EPS) * g.y + bt.y, 0.f);
    }
    {
        float mu = s0.z * invN, var = s1.z * invN - mu * mu;
        r.z = fmaxf((v.z - mu) * rsqrtf(var + BN_EPS) * g.z + bt.z, 0.f);
    }
    {
        float mu = s0.w * invN, var = s1.w * invN - mu * mu;
        r.w = fmaxf((v.w - mu) * rsqrtf(var + BN_EPS) * g.w + bt.w, 0.f);
    }
    if (residual) {
        float4 hv = ((const float4*)h)[idx];
        r.x += hv.x; r.y += hv.y; r.z += hv.z; r.w += hv.w;
    }
    ((float4*)h)[idx] = r;
    if (hh) {
        __half2 p0 = __floats2half2_rn(r.x, r.y);
        __half2 p1 = __floats2half2_rn(r.z, r.w);
        uint2 pk;
        pk.x = __builtin_bit_cast(unsigned int, p0);
        pk.y = __builtin_bit_cast(unsigned int, p1);
        *(uint2*)(hh + (size_t)idx * 4) = pk;
    }
}

// ---------------- graph boundaries (batch is sorted) ----------------
__global__ void k_bounds(const int* __restrict__ batch, int* __restrict__ gstart,
                         int* __restrict__ gend) {
    int r = blockIdx.x * 256 + threadIdx.x;
    if (r >= N_NODES) return;
    int b = batch[r];
    if (r == 0 || batch[r - 1] != b) gstart[b] = r;
    if (r == N_NODES - 1 || batch[r + 1] != b) gend[b] = r + 1;
}

// ---------------- mean pool per graph (wave per graph) ----------------
__global__ void k_pool(const float* __restrict__ h, const int* __restrict__ gstart,
                       const int* __restrict__ gend, float* __restrict__ pooled) {
    int wave = (blockIdx.x * blockDim.x + threadIdx.x) >> 6;
    int lane = threadIdx.x & 63;
    if (wave >= N_GRAPHS) return;
    int g = wave;
    int c = lane * 2;
    int a = gstart[g], b = gend[g];
    float ax = 0.f, ay = 0.f;
    for (int r = a; r < b; ++r) {
        float2 v = *(const float2*)(h + (size_t)r * HID + c);
        ax += v.x;
        ay += v.y;
    }
    float d = fmaxf((float)(b - a), 1.f);
    float2 o;
    o.x = ax / d;
    o.y = ay / d;
    *(float2*)(pooled + (size_t)g * HID + c) = o;
}

// ---------------- head MLP ----------------
__global__ void k_head(const float* __restrict__ pooled, const float* __restrict__ hw1,
                       const float* __restrict__ hb1, const float* __restrict__ hw2,
                       const float* __restrict__ hb2, const float* __restrict__ hw3,
                       const float* __restrict__ hb3, float* __restrict__ out) {
    __shared__ float ps[2][128];
    __shared__ float t1s[2][128];
    __shared__ float red[256];
    int tid = threadIdx.x;
    int rr = tid >> 7, c = tid & 127;
    int row = blockIdx.x * 2 + rr;
    ps[rr][c] = pooled[(size_t)row * 128 + c];
    __syncthreads();
    float a = hb1[c];
    for (int k = 0; k < 128; ++k) a = fmaf(ps[rr][k], hw1[k * 128 + c], a);
    t1s[rr][c] = fmaxf(a, 0.f);
    __syncthreads();
    float b = hb2[c];
    for (int k = 0; k < 128; ++k) b = fmaf(t1s[rr][k], hw2[k * 128 + c], b);
    b = fmaxf(b, 0.f);
    red[tid] = b * hw3[c];
    for (int s = 64; s > 0; s >>= 1) {
        __syncthreads();
        if (c < s) red[tid] += red[tid + s];
    }
    __syncthreads();
    if (c == 0) out[row] = red[tid] + hb3[0];
}

// ---------------- launch ----------------
extern "C" void kernel_launch(void* const* d_in, const int* in_sizes, int n_in,
                              void* d_out, int out_size, void* d_ws, size_t ws_size,
                              hipStream_t stream) {
    const float* x = (const float*)d_in[0];
    const float* edge_attr = (const float*)d_in[1];
    const float* e_w0 = (const float*)d_in[2];
    const float* e_b0 = (const float*)d_in[3];
    const float* w1_0 = (const float*)d_in[4];
    const float* b1_0 = (const float*)d_in[5];
    const float* w2_0 = (const float*)d_in[6];
    const float* b2_0 = (const float*)d_in[7];
    const float* gamma0 = (const float*)d_in[8];
    const float* beta0 = (const float*)d_in[9];
    const float* eps0 = (const float*)d_in[10];
    const float* e_w = (const float*)d_in[11];
    const float* e_b = (const float*)d_in[12];
    const float* w1 = (const float*)d_in[13];
    const float* b1 = (const float*)d_in[14];
    const float* w2 = (const float*)d_in[15];
    const float* b2 = (const float*)d_in[16];
    const float* gamma = (const float*)d_in[17];
    const float* beta = (const float*)d_in[18];
    const float* eps_r = (const float*)d_in[19];
    const float* hw1 = (const float*)d_in[20];
    const float* hb1 = (const float*)d_in[21];
    const float* hw2 = (const float*)d_in[22];
    const float* hb2 = (const float*)d_in[23];
    const float* hw3 = (const float*)d_in[24];
    const float* hb3 = (const float*)d_in[25];
    const int* edge_index = (const int*)d_in[26];
    const int* batch = (const int*)d_in[27];
    float* out = (float*)d_out;

    // workspace layout
    float* wsf = (float*)d_ws;
    size_t off = 0;
    float* A = wsf + off;      off += (size_t)N_NODES * HID;   // h
    float* ZB = wsf + off;     off += (size_t)N_NODES * HID;   // Z / hpre (aliased per-tile)
    float* Z0 = wsf + off;     off += (size_t)N_NODES * IN_DIM;
    float* pooled = wsf + off; off += (size_t)N_GRAPHS * HID;
    float* stats = wsf + off;  off += 5 * 2 * HID;
    float* csr_ea = wsf + off; off += (size_t)3 * N_EDGES;
    __half* hhalf = (__half*)(wsf + off); off += (size_t)N_NODES * HID / 2;  // fp16 shadow
    int* ib = (int*)(wsf + off);
    size_t io = 0;
    int* deg = ib + io;      io += N_NODES;
    int* rowstart = ib + io; io += N_NODES + 4;
    int* cur = ib + io;      io += N_NODES;
    int* csr_src = ib + io;  io += N_EDGES;
    int* gstart = ib + io;   io += N_GRAPHS;
    int* gend = ib + io;     io += N_GRAPHS;
    int* bsum = ib + io;     io += 512;
    int* boff = ib + io;     io += 512;
    unsigned short* Whi = (unsigned short*)(ib + io);          // 10 slots * 16384 ushorts
    unsigned short* Wlo = Whi + 10 * WSLOT;

    const int EB = (N_EDGES + 255) / 256;        // 2344
    const int NB = (N_NODES + 255) / 256;        // 391
    const int MLPB = (N_NODES + 63) / 64;        // 1563

    // zero control buffers + pack weights (ws is poisoned before every call)
    k_zero<<<NB, 256, 0, stream>>>(deg, gstart, gend, stats);
    k_pack<<<320, 64, 0, stream>>>(w1_0, w2_0, w1, w2, Whi, Wlo);

    // CSR build
    k_deg<<<EB, 256, 0, stream>>>(edge_index, deg);
    k_scan_a<<<NBLK, SCAN_BS, 0, stream>>>(deg, rowstart, bsum);
    k_scan_b<<<1, 512, 0, stream>>>(bsum, boff);
    k_scan_c<<<NB, 256, 0, stream>>>(rowstart, boff, cur);
    k_fill<<<EB, 256, 0, stream>>>(edge_index, edge_attr, cur, csr_src, csr_ea);

    // layer 0
    k_agg0<<<(N_NODES * 64) / 256, 256, 0, stream>>>(x, rowstart, csr_src, csr_ea, e_w0,
                                                     e_b0, eps0, Z0);
    k_mlp<IN_DIM><<<MLPB, 256, 0, stream>>>(Z0, Whi + 0 * WSLOT, Wlo + 0 * WSLOT,
                                            Whi + 1 * WSLOT, Wlo + 1 * WSLOT,
                                            b1_0, b2_0, ZB, stats);
    k_bn<<<(N_NODES * HID / 4) / 256, 256, 0, stream>>>(ZB, stats, gamma0, beta0, A,
                                                        hhalf, 0);

    // layers 1..4
    for (int i = 0; i < NREST; ++i) {
        k_agg128<<<(N_NODES * 64) / 256, 256, 0, stream>>>(
            A, hhalf, rowstart, csr_src, csr_ea, e_w + (size_t)i * 3 * HID,
            e_b + (size_t)i * HID, eps_r, i, ZB);
        k_mlp<HID><<<MLPB, 256, 0, stream>>>(ZB, Whi + (size_t)(2 + i) * WSLOT,
                                             Wlo + (size_t)(2 + i) * WSLOT,
                                             Whi + (size_t)(6 + i) * WSLOT,
                                             Wlo + (size_t)(6 + i) * WSLOT,
                                             b1 + (size_t)i * HID, b2 + (size_t)i * HID,
                                             ZB, stats + (size_t)(i + 1) * 2 * HID);
        k_bn<<<(N_NODES * HID / 4) / 256, 256, 0, stream>>>(
            ZB, stats + (size_t)(i + 1) * 2 * HID, gamma + (size_t)i * HID,
            beta + (size_t)i * HID, A, (i < NREST - 1) ? hhalf : (__half*)nullptr, 1);
    }

    // pooling + head
    k_bounds<<<NB, 256, 0, stream>>>(batch, gstart, gend);
    k_pool<<<(N_GRAPHS * 64) / 256, 256, 0, stream>>>(A, gstart, gend, pooled);
    k_head<<<N_GRAPHS / 2, 256, 0, stream>>>(pooled, hw1, hb1, hw2, hb2, hw3, hb3, out);
}